// Round 5
// baseline (3096.096 us; speedup 1.0000x reference)
//
#include <hip/hip_runtime.h>
#include <hip/hip_bf16.h>
#include <stdint.h>

// Problem constants
#define BATCH 4096
#define HW 784          // 28*28
#define IMW 28
#define NCELL 196       // 14*14
#define K_FC 12544
#define LMAX 655360     // active-site list capacity (expected ~642,253 = mean+18sigma)

// Workspace layout (bytes). Peak 204 MiB (verified to fit: R4 ran with this layout).
#define OFF_FLAG    0ull               // mask storage format
#define OFF_CNT     4ull               // active-site counter
#define OFF_IFMT    8ull               // input float format: 0=f32, 1=bf16
#define OFF_W1T     1024ull            // f32[9][32]        1152 B
#define OFF_W2T     4096ull            // f32[9][32][64]    73728 B (ends 77824)
#define OFF_FC2T    81920ull           // f32[128][10]      5120 B
#define OFF_H3      (512ull<<10)       // f32[128][4096]    2 MiB (ends 2.5M)
#define OFF_FC1T    (3ull<<20)         // f32[12544][128]   6.125 MiB (ends 9.125M)
#define OFF_IDX     (10ull<<20)        // i32[784][4096]    12.25 MiB (ends 22.25M)
#define OFF_LIST    (23ull<<20)        // u32[LMAX]         2.5 MiB (ends 25.5M)
#define OFF_COMPACT (26ull<<20)        // bf16[LMAX][64]    80 MiB (ends 106M)
#define OFF_PARTIAL (26ull<<20)        // f32[16*128][4096] 32 MiB — aliases COMPACT (dead by then)
#define OFF_H1C     (106ull<<20)       // bf16[LMAX][32]    40 MiB (ends 146M)
#define OFF_POOLED  (106ull<<20)       // bf16[12544][4096] 98 MiB — aliases H1C (dead by then), ends 204M

__device__ __forceinline__ float bflo(uint32_t u){ return __uint_as_float(u << 16); }
__device__ __forceinline__ float bfhi(uint32_t u){ return __uint_as_float(u & 0xFFFF0000u); }
__device__ __forceinline__ float bfu16(uint16_t h){ return __uint_as_float(((uint32_t)h) << 16); }
__device__ __forceinline__ uint32_t f2bf(float f){
    uint32_t u = __float_as_uint(f);
    return (u + 0x7FFFu + ((u >> 16) & 1u)) >> 16;   // RNE
}
__device__ __forceinline__ uint32_t packbf(float a, float b){
    return f2bf(a) | (f2bf(b) << 16);
}

// Input float tensor load honoring probed storage format (0=f32, 1=bf16)
__device__ __forceinline__ float ldin(const void* p, size_t i, int ifmt){
    return ifmt ? bfu16(((const uint16_t*)p)[i]) : ((const float*)p)[i];
}

// mask storage: 0 = u8 bytes, 1 = int32, 2 = f32 (0/1.0f), 3 = bf16 (0/0x3F80)
__device__ __forceinline__ bool mask_active(const void* mp, int pix, int flag){
    if (flag == 1) return ((const int*)mp)[pix] != 0;
    if (flag == 0) return ((const uint8_t*)mp)[pix] != 0;
    if (flag == 2) return ((const uint32_t*)mp)[pix] != 0u;
    return ((const uint16_t*)mp)[pix] != 0;
}

// ---------------- P0: probes (mask format, input float format), CNT=0 --------------
__global__ __launch_bounds__(256) void probe_k(const void* __restrict__ mask,
                                               const void* __restrict__ fc1w,
                                               uint8_t* __restrict__ ws){
    __shared__ int s_gt1, s_byte, s_f32, s_half, s_bad;
    if (threadIdx.x == 0){ s_gt1=0; s_byte=0; s_f32=0; s_half=0; s_bad=0;
                           *(int*)(ws + OFF_CNT) = 0; }
    __syncthreads();

    // --- mask format probe over first 64 KB ---
    const uint32_t* mw = (const uint32_t*)mask;
    int gt1 = 0, bbyte = 0, bf32 = 0, bhalf = 0;
    for (int i = threadIdx.x; i < 16384; i += 256){
        uint32_t w = mw[i];
        if (w > 1u) gt1 = 1;
        uint32_t b0 = w & 0xFFu, b1 = (w>>8)&0xFFu, b2 = (w>>16)&0xFFu, b3 = w>>24;
        if (b0>1u || b1>1u || b2>1u || b3>1u) bbyte = 1;
        if (w != 0u && w != 0x3F800000u) bf32 = 1;
        uint32_t h0 = w & 0xFFFFu, h1 = w >> 16;
        if ((h0 != 0u && h0 != 0x3F80u) || (h1 != 0u && h1 != 0x3F80u)) bhalf = 1;
    }
    if (gt1)   atomicOr(&s_gt1, 1);
    if (bbyte) atomicOr(&s_byte, 1);
    if (bf32)  atomicOr(&s_f32, 1);
    if (bhalf) atomicOr(&s_half, 1);

    // --- input float format probe on fc1w (values ~N(0, 0.01), never exactly 0) ---
    // bf16 storage: every nonzero u16 half has a sane exponent. f32 storage: low
    // halves are random mantissa bits -> ~43% implausible as bf16 -> large s_bad.
    const uint32_t* fw = (const uint32_t*)fc1w;
    int bad = 0;
    for (int i = threadIdx.x; i < 4096; i += 256){
        uint32_t w = fw[i];
        uint32_t h0 = w & 0xFFFFu, h1 = w >> 16;
        uint32_t e0 = (h0 >> 7) & 0xFFu, e1 = (h1 >> 7) & 0xFFu;
        if (h0 != 0u && (e0 >= 0xF0u || e0 < 0x5Eu)) bad++;  // |v|>1e34 or |v|<1e-10
        if (h1 != 0u && (e1 >= 0xF0u || e1 < 0x5Eu)) bad++;
    }
    if (bad) atomicAdd(&s_bad, bad);
    __syncthreads();

    if (threadIdx.x == 0){
        int flag;
        if      (!s_gt1)  flag = 1;   // all words 0/1      -> int32
        else if (!s_byte) flag = 0;   // all bytes 0/1      -> u8
        else if (!s_f32)  flag = 2;   // all words 0/1.0f   -> f32
        else if (!s_half) flag = 3;   // all halves 0/0x3F80-> bf16
        else              flag = 0;
        *(int*)(ws + OFF_FLAG) = flag;
        *(int*)(ws + OFF_IFMT) = (s_bad < 400) ? 1 : 0;   // few bad halves -> bf16
    }
}

// ---------------- P1: weight transposes to f32 scratch -----------------------------
__global__ __launch_bounds__(256) void prep_k(const void* __restrict__ w1,
                                              const void* __restrict__ w2,
                                              const void* __restrict__ fc1w,
                                              const void* __restrict__ fc2w,
                                              uint8_t* __restrict__ ws){
    int t = blockIdx.x * 256 + threadIdx.x;
    int ifmt = *(volatile int*)(ws + OFF_IFMT);
    float* w1t  = (float*)(ws + OFF_W1T);
    float* w2t  = (float*)(ws + OFF_W2T);
    float* fc1t = (float*)(ws + OFF_FC1T);
    float* fc2t = (float*)(ws + OFF_FC2T);

    if (t < 288){                       // W1T[tap][oc] <- W1[oc][0][tap]
        int tap = t >> 5, oc = t & 31;
        w1t[t] = ldin(w1, oc*9 + tap, ifmt);
    }
    if (t < 18432){                     // W2T[tap][ic][oc] <- W2[oc][ic][tap]
        int oc = t & 63, ic = (t >> 6) & 31, tap = t >> 11;
        w2t[t] = ldin(w2, (oc*32 + ic)*9 + tap, ifmt);
    }
    if (t < 1280){                      // FC2T[k][n] <- fc2w[n][k]
        int k = t / 10, n = t - k*10;
        fc2t[t] = ldin(fc2w, n*128 + k, ifmt);
    }
    if (t < 1605632){                   // FC1T[k][n] <- fc1w[n][k]
        int k = t >> 7, n = t & 127;
        fc1t[t] = ldin(fc1w, (size_t)n*K_FC + k, ifmt);
    }
}

// ---------------- K1: compact active pixels -> CNT, LIST, IDX map ------------------
__global__ __launch_bounds__(256) void compact_k(const void* __restrict__ mask,
                                                 uint8_t* __restrict__ ws){
    int t = blockIdx.x * 256 + threadIdx.x;            // pixel id = b*784 + yx
    int flag = *(volatile int*)(ws + OFF_FLAG);
    int b = t / HW; int yx = t - b*HW;
    bool act = mask_active(mask, t, flag);
    int idx = -1;
    if (act){
        idx = atomicAdd((int*)(ws + OFF_CNT), 1);
        if (idx < LMAX) ((uint32_t*)(ws + OFF_LIST))[idx] = ((uint32_t)yx << 12) | (uint32_t)b;
        else idx = -1;
    }
    ((int*)(ws + OFF_IDX))[(size_t)yx*BATCH + b] = idx;
}

// ---------------- K2: conv1 (1->32) + relu at active sites -> H1C bf16 -------------
__global__ __launch_bounds__(256) void conv1_k(const void* __restrict__ x,
                                               uint8_t* __restrict__ ws){
    int e = blockIdx.x * 256 + threadIdx.x;
    int count = *(volatile int*)(ws + OFF_CNT);
    if (count > LMAX) count = LMAX;
    if (e >= count) return;
    int ifmt = *(volatile int*)(ws + OFF_IFMT);
    const float* w1t = (const float*)(ws + OFF_W1T);
    uint32_t code = ((const uint32_t*)(ws + OFF_LIST))[e];
    int b = code & 4095; int yx = code >> 12;
    int y = yx / IMW; int xx = yx - y*IMW;

    float acc[32];
    #pragma unroll
    for (int i = 0; i < 32; i++) acc[i] = 0.f;
    #pragma unroll
    for (int ky = 0; ky < 3; ky++){
        #pragma unroll
        for (int kx = 0; kx < 3; kx++){
            int ny = y + ky - 1, nx = xx + kx - 1;
            bool inb = ((unsigned)ny < 28u) && ((unsigned)nx < 28u);
            float xv = inb ? ldin(x, (size_t)b*HW + ny*IMW + nx, ifmt) : 0.f;
            const float* wt = w1t + (ky*3 + kx)*32;
            #pragma unroll
            for (int oc = 0; oc < 32; oc++) acc[oc] = fmaf(xv, wt[oc], acc[oc]);
        }
    }
    uint32_t o[16];
    #pragma unroll
    for (int i = 0; i < 16; i++)
        o[i] = packbf(fmaxf(acc[2*i], 0.f), fmaxf(acc[2*i+1], 0.f));
    uint4* dst = (uint4*)(ws + OFF_H1C + (size_t)e*64);
    dst[0] = make_uint4(o[0],o[1],o[2],o[3]);
    dst[1] = make_uint4(o[4],o[5],o[6],o[7]);
    dst[2] = make_uint4(o[8],o[9],o[10],o[11]);
    dst[3] = make_uint4(o[12],o[13],o[14],o[15]);
}

// ---------------- K3: conv2 (32->64) at active sites via IDX gathers ---------------
__global__ __launch_bounds__(256) void conv2_k(uint8_t* __restrict__ ws){
    int e = blockIdx.x * 256 + threadIdx.x;
    int count = *(volatile int*)(ws + OFF_CNT);
    if (count > LMAX) count = LMAX;
    if (e >= count) return;
    const float*    w2t  = (const float*)(ws + OFF_W2T);
    const uint32_t* h1c  = (const uint32_t*)(ws + OFF_H1C);
    const int*      imap = (const int*)(ws + OFF_IDX);
    uint32_t code = ((const uint32_t*)(ws + OFF_LIST))[e];
    int b = code & 4095; int yx = code >> 12;
    int y = yx / IMW; int xx = yx - y*IMW;

    #pragma unroll
    for (int pass = 0; pass < 2; pass++){            // oc 0..31, then 32..63
        float acc[32];
        #pragma unroll
        for (int i = 0; i < 32; i++) acc[i] = 0.f;
        for (int tap = 0; tap < 9; tap++){
            int dy = tap/3 - 1, dx = tap - (tap/3)*3 - 1;
            int ny = y + dy, nx = xx + dx;
            bool inb = ((unsigned)ny < 28u) && ((unsigned)nx < 28u);
            int nidx = inb ? imap[(size_t)(ny*IMW + nx)*BATCH + b] : -1;
            uint32_t hv[16];
            if (nidx >= 0){
                const uint4* q = (const uint4*)(h1c + (size_t)nidx*16);
                uint4 a = q[0], c = q[1], d = q[2], f = q[3];
                hv[0]=a.x; hv[1]=a.y; hv[2]=a.z; hv[3]=a.w;
                hv[4]=c.x; hv[5]=c.y; hv[6]=c.z; hv[7]=c.w;
                hv[8]=d.x; hv[9]=d.y; hv[10]=d.z; hv[11]=d.w;
                hv[12]=f.x; hv[13]=f.y; hv[14]=f.z; hv[15]=f.w;
            } else {
                #pragma unroll
                for (int i = 0; i < 16; i++) hv[i] = 0u;
            }
            const float* wt = w2t + tap*2048 + pass*32;
            #pragma unroll
            for (int icp = 0; icp < 16; icp++){
                float v0 = bflo(hv[icp]), v1 = bfhi(hv[icp]);
                const float* wa = wt + (2*icp)*64;
                const float* wb = wt + (2*icp+1)*64;
                #pragma unroll
                for (int oc = 0; oc < 32; oc++) acc[oc] = fmaf(v0, wa[oc], acc[oc]);
                #pragma unroll
                for (int oc = 0; oc < 32; oc++) acc[oc] = fmaf(v1, wb[oc], acc[oc]);
            }
        }
        uint32_t o[16];
        #pragma unroll
        for (int i = 0; i < 16; i++)
            o[i] = packbf(fmaxf(acc[2*i], 0.f), fmaxf(acc[2*i+1], 0.f));
        uint4* dst = (uint4*)(ws + OFF_COMPACT + (size_t)e*128 + (size_t)pass*64);
        dst[0] = make_uint4(o[0],o[1],o[2],o[3]);
        dst[1] = make_uint4(o[4],o[5],o[6],o[7]);
        dst[2] = make_uint4(o[8],o[9],o[10],o[11]);
        dst[3] = make_uint4(o[12],o[13],o[14],o[15]);
    }
}

// ---------------- K4: maxpool 2x2 -> pooledT[k=oc*196+cell][b] bf16 ----------------
__global__ __launch_bounds__(256) void pool_k(uint8_t* __restrict__ ws){
    int t = blockIdx.x * 256 + threadIdx.x;  // t = cell*4096 + b
    int b = t & 4095; int cell = t >> 12;
    int py = cell / 14, px = cell - py*14;
    const int* imap = (const int*)(ws + OFF_IDX);
    float mx[64];
    #pragma unroll
    for (int i = 0; i < 64; i++) mx[i] = 0.f;
    #pragma unroll
    for (int s = 0; s < 4; s++){
        int yy = 2*py + (s >> 1), xxp = 2*px + (s & 1);
        int idx = imap[(size_t)(yy*IMW + xxp)*BATCH + b];
        if (idx >= 0){
            const uint4* row = (const uint4*)(ws + OFF_COMPACT + (size_t)idx*128);
            #pragma unroll
            for (int q = 0; q < 8; q++){
                uint4 v = row[q];
                mx[q*8+0] = fmaxf(mx[q*8+0], bflo(v.x)); mx[q*8+1] = fmaxf(mx[q*8+1], bfhi(v.x));
                mx[q*8+2] = fmaxf(mx[q*8+2], bflo(v.y)); mx[q*8+3] = fmaxf(mx[q*8+3], bfhi(v.y));
                mx[q*8+4] = fmaxf(mx[q*8+4], bflo(v.z)); mx[q*8+5] = fmaxf(mx[q*8+5], bfhi(v.z));
                mx[q*8+6] = fmaxf(mx[q*8+6], bflo(v.w)); mx[q*8+7] = fmaxf(mx[q*8+7], bfhi(v.w));
            }
        }
    }
    uint16_t* pooled = (uint16_t*)(ws + OFF_POOLED);
    #pragma unroll
    for (int oc = 0; oc < 64; oc++)
        pooled[(size_t)(oc*NCELL + cell)*BATCH + b] = (uint16_t)f2bf(mx[oc]);
}

// ---------------- K5: fc1 GEMM partials (k-split x16, n-quarters x4) ---------------
__global__ __launch_bounds__(256) void fc1_k(uint8_t* __restrict__ ws){
    int gw   = (blockIdx.x * 256 + threadIdx.x) >> 6;
    int lane = threadIdx.x & 63;
    int bg = gw & 63, nq = (gw >> 6) & 3, kc = gw >> 8;   // 64 x 4 x 16 = 4096 waves
    int b = bg*64 + lane;
    const uint16_t* pooled = (const uint16_t*)(ws + OFF_POOLED);
    const float*    fc1t   = (const float*)(ws + OFF_FC1T);
    float acc[32];
    #pragma unroll
    for (int i = 0; i < 32; i++) acc[i] = 0.f;
    int k0 = kc * 784;
    for (int k = k0; k < k0 + 784; k++){
        float v = bfu16(pooled[(size_t)k*BATCH + b]);
        const float* wk = fc1t + (size_t)k*128 + nq*32;
        #pragma unroll
        for (int j = 0; j < 32; j++) acc[j] = fmaf(v, wk[j], acc[j]);
    }
    float* partial = (float*)(ws + OFF_PARTIAL);
    #pragma unroll
    for (int j = 0; j < 32; j++)
        partial[(size_t)(kc*128 + nq*32 + j)*BATCH + b] = acc[j];
}

// ---------------- K5b: reduce partials + bias + relu -> h3T[n][b] f32 --------------
__global__ __launch_bounds__(256) void fc1red_k(const void* __restrict__ fc1b,
                                                uint8_t* __restrict__ ws){
    int t = blockIdx.x * 256 + threadIdx.x;  // t = n*4096 + b
    int b = t & 4095; int n = t >> 12;
    int ifmt = *(volatile int*)(ws + OFF_IFMT);
    const float* partial = (const float*)(ws + OFF_PARTIAL);
    float s = ldin(fc1b, n, ifmt);
    #pragma unroll
    for (int kc = 0; kc < 16; kc++) s += partial[(size_t)(kc*128 + n)*BATCH + b];
    ((float*)(ws + OFF_H3))[t] = fmaxf(s, 0.f);
}

// ---------------- K6: fc2 + log_softmax -> out [B][10] f32 -------------------------
__global__ __launch_bounds__(256) void fc2_k(const void* __restrict__ fc2b,
                                             uint8_t* __restrict__ ws,
                                             float* __restrict__ out){
    int b = blockIdx.x * 256 + threadIdx.x;  // 4096 threads
    int ifmt = *(volatile int*)(ws + OFF_IFMT);
    const float* h3   = (const float*)(ws + OFF_H3);
    const float* fc2t = (const float*)(ws + OFF_FC2T);
    float acc[10];
    #pragma unroll
    for (int n = 0; n < 10; n++) acc[n] = ldin(fc2b, n, ifmt);
    for (int k = 0; k < 128; k++){
        float v = h3[(size_t)k*BATCH + b];
        const float* wk = fc2t + k*10;
        #pragma unroll
        for (int n = 0; n < 10; n++) acc[n] = fmaf(v, wk[n], acc[n]);
    }
    float m = acc[0];
    #pragma unroll
    for (int n = 1; n < 10; n++) m = fmaxf(m, acc[n]);
    float s = 0.f;
    #pragma unroll
    for (int n = 0; n < 10; n++) s += expf(acc[n] - m);
    float ls = logf(s);
    #pragma unroll
    for (int n = 0; n < 10; n++) out[(size_t)b*10 + n] = acc[n] - m - ls;
}

extern "C" void kernel_launch(void* const* d_in, const int* in_sizes, int n_in,
                              void* d_out, int out_size, void* d_ws, size_t ws_size,
                              hipStream_t stream){
    const void* x    = d_in[0];
    const void* mask = d_in[1];
    const void* w1   = d_in[2];
    const void* w2   = d_in[3];
    const void* fc1w = d_in[4];
    const void* fc1b = d_in[5];
    const void* fc2w = d_in[6];
    const void* fc2b = d_in[7];
    uint8_t* ws = (uint8_t*)d_ws;
    float* out = (float*)d_out;

    hipLaunchKernelGGL(probe_k,   dim3(1),     dim3(256), 0, stream, mask, fc1w, ws);
    hipLaunchKernelGGL(prep_k,    dim3(6272),  dim3(256), 0, stream, w1, w2, fc1w, fc2w, ws);
    hipLaunchKernelGGL(compact_k, dim3(12544), dim3(256), 0, stream, mask, ws);
    hipLaunchKernelGGL(conv1_k,   dim3(2560),  dim3(256), 0, stream, x, ws);
    hipLaunchKernelGGL(conv2_k,   dim3(2560),  dim3(256), 0, stream, ws);
    hipLaunchKernelGGL(pool_k,    dim3(3136),  dim3(256), 0, stream, ws);
    hipLaunchKernelGGL(fc1_k,     dim3(1024),  dim3(256), 0, stream, ws);
    hipLaunchKernelGGL(fc1red_k,  dim3(2048),  dim3(256), 0, stream, fc1b, ws);
    hipLaunchKernelGGL(fc2_k,     dim3(16),    dim3(256), 0, stream, fc2b, ws, out);
}

// Round 6
// 2407.506 us; speedup vs baseline: 1.2860x; 1.2860x over previous
//
#include <hip/hip_runtime.h>
#include <hip/hip_bf16.h>
#include <stdint.h>

// Problem constants
#define BATCH 4096
#define HW 784          // 28*28
#define IMW 28
#define NCELL 196       // 14*14
#define K_FC 12544
#define LMAX 655360     // active-site list capacity (expected ~642,253 = mean+18sigma)

// Workspace layout (bytes). Base peak 204 MiB (known to fit); IDX_YB (12.25 MiB)
// appended at 204M only if ws_size allows, else pool falls back to strided reads.
#define OFF_FLAG    0ull               // mask storage format
#define OFF_CNT     4ull               // active-site counter
#define OFF_IFMT    8ull               // input float format: 0=f32, 1=bf16
#define OFF_W1T     1024ull            // f32[9][32]        1152 B
#define OFF_W2T     4096ull            // f32[9][32][64]    73728 B (ends 77824)
#define OFF_FC2T    81920ull           // f32[128][10]      5120 B
#define OFF_H3      (512ull<<10)       // f32[128][4096]    2 MiB (ends 2.5M)
#define OFF_FC1T    (3ull<<20)         // f32[12544][128]   6.125 MiB (ends 9.125M)
#define OFF_IDX     (10ull<<20)        // i32[4096][784]  (b-major!) 12.25 MiB (ends 22.25M)
#define OFF_LIST    (23ull<<20)        // u32[LMAX]         2.5 MiB (ends 25.5M)
#define OFF_COMPACT (26ull<<20)        // bf16[LMAX][64]    80 MiB (ends 106M)
#define OFF_PARTIAL (26ull<<20)        // f32[16*128][4096] 32 MiB — aliases COMPACT (dead by then)
#define OFF_H1C     (106ull<<20)       // bf16[LMAX][32]    40 MiB (ends 146M)
#define OFF_POOLED  (106ull<<20)       // bf16[12544][4096] 98 MiB — aliases H1C (dead), ends 204M
#define OFF_IDXYB   (204ull<<20)       // i32[784][4096]  (yx-major, for pool) 12.25 MiB if room

__device__ __forceinline__ float bflo(uint32_t u){ return __uint_as_float(u << 16); }
__device__ __forceinline__ float bfhi(uint32_t u){ return __uint_as_float(u & 0xFFFF0000u); }
__device__ __forceinline__ float bfu16(uint16_t h){ return __uint_as_float(((uint32_t)h) << 16); }
__device__ __forceinline__ uint32_t f2bf(float f){
    uint32_t u = __float_as_uint(f);
    return (u + 0x7FFFu + ((u >> 16) & 1u)) >> 16;   // RNE
}
__device__ __forceinline__ uint32_t packbf(float a, float b){
    return f2bf(a) | (f2bf(b) << 16);
}

// Input float tensor load honoring probed storage format (0=f32, 1=bf16)
__device__ __forceinline__ float ldin(const void* p, size_t i, int ifmt){
    return ifmt ? bfu16(((const uint16_t*)p)[i]) : ((const float*)p)[i];
}

// mask storage: 0 = u8 bytes, 1 = int32, 2 = f32 (0/1.0f), 3 = bf16 (0/0x3F80)
__device__ __forceinline__ bool mask_active(const void* mp, int pix, int flag){
    if (flag == 1) return ((const int*)mp)[pix] != 0;
    if (flag == 0) return ((const uint8_t*)mp)[pix] != 0;
    if (flag == 2) return ((const uint32_t*)mp)[pix] != 0u;
    return ((const uint16_t*)mp)[pix] != 0;
}

// ---------------- P0: probes (mask format, input float format), CNT=0 --------------
__global__ __launch_bounds__(256) void probe_k(const void* __restrict__ mask,
                                               const void* __restrict__ fc1w,
                                               uint8_t* __restrict__ ws){
    __shared__ int s_gt1, s_byte, s_f32, s_half, s_bad;
    if (threadIdx.x == 0){ s_gt1=0; s_byte=0; s_f32=0; s_half=0; s_bad=0;
                           *(int*)(ws + OFF_CNT) = 0; }
    __syncthreads();
    const uint32_t* mw = (const uint32_t*)mask;
    int gt1 = 0, bbyte = 0, bf32 = 0, bhalf = 0;
    for (int i = threadIdx.x; i < 16384; i += 256){
        uint32_t w = mw[i];
        if (w > 1u) gt1 = 1;
        uint32_t b0 = w & 0xFFu, b1 = (w>>8)&0xFFu, b2 = (w>>16)&0xFFu, b3 = w>>24;
        if (b0>1u || b1>1u || b2>1u || b3>1u) bbyte = 1;
        if (w != 0u && w != 0x3F800000u) bf32 = 1;
        uint32_t h0 = w & 0xFFFFu, h1 = w >> 16;
        if ((h0 != 0u && h0 != 0x3F80u) || (h1 != 0u && h1 != 0x3F80u)) bhalf = 1;
    }
    if (gt1)   atomicOr(&s_gt1, 1);
    if (bbyte) atomicOr(&s_byte, 1);
    if (bf32)  atomicOr(&s_f32, 1);
    if (bhalf) atomicOr(&s_half, 1);

    const uint32_t* fw = (const uint32_t*)fc1w;
    int bad = 0;
    for (int i = threadIdx.x; i < 4096; i += 256){
        uint32_t w = fw[i];
        uint32_t h0 = w & 0xFFFFu, h1 = w >> 16;
        uint32_t e0 = (h0 >> 7) & 0xFFu, e1 = (h1 >> 7) & 0xFFu;
        if (h0 != 0u && (e0 >= 0xF0u || e0 < 0x5Eu)) bad++;
        if (h1 != 0u && (e1 >= 0xF0u || e1 < 0x5Eu)) bad++;
    }
    if (bad) atomicAdd(&s_bad, bad);
    __syncthreads();
    if (threadIdx.x == 0){
        int flag;
        if      (!s_gt1)  flag = 1;
        else if (!s_byte) flag = 0;
        else if (!s_f32)  flag = 2;
        else if (!s_half) flag = 3;
        else              flag = 0;
        *(int*)(ws + OFF_FLAG) = flag;
        *(int*)(ws + OFF_IFMT) = (s_bad < 400) ? 1 : 0;
    }
}

// ---------------- P1: small weight transposes (w1, w2, fc2) ------------------------
__global__ __launch_bounds__(256) void prep_k(const void* __restrict__ w1,
                                              const void* __restrict__ w2,
                                              const void* __restrict__ fc2w,
                                              uint8_t* __restrict__ ws){
    int t = blockIdx.x * 256 + threadIdx.x;
    int ifmt = *(volatile int*)(ws + OFF_IFMT);
    float* w1t  = (float*)(ws + OFF_W1T);
    float* w2t  = (float*)(ws + OFF_W2T);
    float* fc2t = (float*)(ws + OFF_FC2T);
    if (t < 288){                       // W1T[tap][oc] <- W1[oc][0][tap]
        int tap = t >> 5, oc = t & 31;
        w1t[t] = ldin(w1, oc*9 + tap, ifmt);
    }
    if (t < 18432){                     // W2T[tap][ic][oc] <- W2[oc][ic][tap]
        int oc = t & 63, ic = (t >> 6) & 31, tap = t >> 11;
        w2t[t] = ldin(w2, (oc*32 + ic)*9 + tap, ifmt);
    }
    if (t < 1280){                      // FC2T[k][n] <- fc2w[n][k]
        int k = t / 10, n = t - k*10;
        fc2t[t] = ldin(fc2w, n*128 + k, ifmt);
    }
}

// ---------------- P2: fc1w transpose via LDS tiles: [128][12544] -> [12544][128] ---
__global__ __launch_bounds__(256) void fc1t_k(const void* __restrict__ fc1w,
                                              uint8_t* __restrict__ ws){
    __shared__ float tile[16][17];
    int ifmt = *(volatile int*)(ws + OFF_IFMT);
    int tx = threadIdx.x & 15, ty = threadIdx.x >> 4;
    int k0 = blockIdx.x * 16;           // 784 blocks over k
    int n0 = blockIdx.y * 16;           // 8 blocks over n
    // read: lane varies k -> coalesced
    tile[ty][tx] = ldin(fc1w, (size_t)(n0 + ty)*K_FC + (k0 + tx), ifmt);
    __syncthreads();
    // write: lane varies n -> coalesced
    float* fc1t = (float*)(ws + OFF_FC1T);
    fc1t[(size_t)(k0 + ty)*128 + (n0 + tx)] = tile[tx][ty];
}

// ---------------- K1: compact active pixels -> CNT, LIST, IDX_BY -------------------
__global__ __launch_bounds__(256) void compact_k(const void* __restrict__ mask,
                                                 uint8_t* __restrict__ ws){
    int t = blockIdx.x * 256 + threadIdx.x;            // pixel id = b*784 + yx
    int flag = *(volatile int*)(ws + OFF_FLAG);
    int b = t / HW; int yx = t - b*HW;
    bool act = mask_active(mask, t, flag);
    int idx = -1;
    if (act){
        idx = atomicAdd((int*)(ws + OFF_CNT), 1);
        if (idx < LMAX) ((uint32_t*)(ws + OFF_LIST))[idx] = ((uint32_t)yx << 12) | (uint32_t)b;
        else idx = -1;
    }
    ((int*)(ws + OFF_IDX))[t] = idx;    // [b][yx], coalesced (lane varies yx)
}

// ---------------- K1b: transpose IDX_BY [b][yx] -> IDX_YB [yx][b] for pool ---------
__global__ __launch_bounds__(256) void idxT_k(uint8_t* __restrict__ ws, int* __restrict__ dst){
    __shared__ int tile[16][17];
    int tx = threadIdx.x & 15, ty = threadIdx.x >> 4;
    int yx0 = blockIdx.x * 16;          // 49 blocks over yx
    int b0  = blockIdx.y * 16;          // 256 blocks over b
    const int* src = (const int*)(ws + OFF_IDX);
    tile[ty][tx] = src[(size_t)(b0 + ty)*HW + (yx0 + tx)];   // lane varies yx ✓
    __syncthreads();
    dst[(size_t)(yx0 + ty)*BATCH + (b0 + tx)] = tile[tx][ty]; // lane varies b ✓
}

// ---------------- K2: conv1 (1->32) + relu at active sites -> H1C bf16 -------------
__global__ __launch_bounds__(256) void conv1_k(const void* __restrict__ x,
                                               uint8_t* __restrict__ ws){
    int e = blockIdx.x * 256 + threadIdx.x;
    int count = *(volatile int*)(ws + OFF_CNT);
    if (count > LMAX) count = LMAX;
    if (e >= count) return;
    int ifmt = *(volatile int*)(ws + OFF_IFMT);
    const float* w1t = (const float*)(ws + OFF_W1T);
    uint32_t code = ((const uint32_t*)(ws + OFF_LIST))[e];
    int b = code & 4095; int yx = code >> 12;
    int y = yx / IMW; int xx = yx - y*IMW;

    float acc[32];
    #pragma unroll
    for (int i = 0; i < 32; i++) acc[i] = 0.f;
    #pragma unroll
    for (int ky = 0; ky < 3; ky++){
        #pragma unroll
        for (int kx = 0; kx < 3; kx++){
            int ny = y + ky - 1, nx = xx + kx - 1;
            bool inb = ((unsigned)ny < 28u) && ((unsigned)nx < 28u);
            float xv = inb ? ldin(x, (size_t)b*HW + ny*IMW + nx, ifmt) : 0.f;
            const float* wt = w1t + (ky*3 + kx)*32;
            #pragma unroll
            for (int oc = 0; oc < 32; oc++) acc[oc] = fmaf(xv, wt[oc], acc[oc]);
        }
    }
    uint32_t o[16];
    #pragma unroll
    for (int i = 0; i < 16; i++)
        o[i] = packbf(fmaxf(acc[2*i], 0.f), fmaxf(acc[2*i+1], 0.f));
    uint4* dst = (uint4*)(ws + OFF_H1C + (size_t)e*64);
    dst[0] = make_uint4(o[0],o[1],o[2],o[3]);
    dst[1] = make_uint4(o[4],o[5],o[6],o[7]);
    dst[2] = make_uint4(o[8],o[9],o[10],o[11]);
    dst[3] = make_uint4(o[12],o[13],o[14],o[15]);
}

// ---------------- K3: conv2 (32->64) at active sites, fused oc, coalesced imap -----
__global__ __launch_bounds__(256) void conv2_k(uint8_t* __restrict__ ws){
    int e = blockIdx.x * 256 + threadIdx.x;
    int count = *(volatile int*)(ws + OFF_CNT);
    if (count > LMAX) count = LMAX;
    if (e >= count) return;
    const float*    w2t  = (const float*)(ws + OFF_W2T);
    const uint32_t* h1c  = (const uint32_t*)(ws + OFF_H1C);
    const int*      imap = (const int*)(ws + OFF_IDX);   // [b][yx]
    uint32_t code = ((const uint32_t*)(ws + OFF_LIST))[e];
    int b = code & 4095; int yx = code >> 12;
    int y = yx / IMW; int xx = yx - y*IMW;
    const int* imb = imap + (size_t)b*HW;

    // prefetch all 9 neighbor indices (coalesced: lane ~ consecutive yx, same b)
    int nidx[9];
    #pragma unroll
    for (int tap = 0; tap < 9; tap++){
        int dy = tap/3 - 1, dx = tap - (tap/3)*3 - 1;
        int ny = y + dy, nx = xx + dx;
        bool inb = ((unsigned)ny < 28u) && ((unsigned)nx < 28u);
        nidx[tap] = inb ? imb[ny*IMW + nx] : -1;
    }

    float acc[64];
    #pragma unroll
    for (int i = 0; i < 64; i++) acc[i] = 0.f;
    for (int tap = 0; tap < 9; tap++){
        int ni = nidx[tap];
        uint32_t hv[16];
        if (ni >= 0){
            const uint4* q = (const uint4*)(h1c + (size_t)ni*16);
            uint4 a = q[0], c = q[1], d = q[2], f = q[3];
            hv[0]=a.x; hv[1]=a.y; hv[2]=a.z; hv[3]=a.w;
            hv[4]=c.x; hv[5]=c.y; hv[6]=c.z; hv[7]=c.w;
            hv[8]=d.x; hv[9]=d.y; hv[10]=d.z; hv[11]=d.w;
            hv[12]=f.x; hv[13]=f.y; hv[14]=f.z; hv[15]=f.w;
        } else {
            #pragma unroll
            for (int i = 0; i < 16; i++) hv[i] = 0u;
        }
        const float* wt = w2t + tap*2048;
        #pragma unroll 4
        for (int icp = 0; icp < 16; icp++){
            float v0 = bflo(hv[icp]), v1 = bfhi(hv[icp]);
            const float* wa = wt + (2*icp)*64;
            const float* wb = wa + 64;
            #pragma unroll
            for (int oc = 0; oc < 64; oc++){
                acc[oc] = fmaf(v0, wa[oc], acc[oc]);
                acc[oc] = fmaf(v1, wb[oc], acc[oc]);
            }
        }
    }
    uint32_t o[32];
    #pragma unroll
    for (int i = 0; i < 32; i++)
        o[i] = packbf(fmaxf(acc[2*i], 0.f), fmaxf(acc[2*i+1], 0.f));
    uint4* dst = (uint4*)(ws + OFF_COMPACT + (size_t)e*128);
    #pragma unroll
    for (int q = 0; q < 8; q++)
        dst[q] = make_uint4(o[4*q], o[4*q+1], o[4*q+2], o[4*q+3]);
}

// ---------------- K4: maxpool 2x2 -> pooledT[k=oc*196+cell][b] bf16 ----------------
__global__ __launch_bounds__(256) void pool_k(uint8_t* __restrict__ ws,
                                              const int* __restrict__ imapP, int yb){
    int t = blockIdx.x * 256 + threadIdx.x;  // t = cell*4096 + b
    int b = t & 4095; int cell = t >> 12;
    int py = cell / 14, px = cell - py*14;
    float mx[64];
    #pragma unroll
    for (int i = 0; i < 64; i++) mx[i] = 0.f;
    #pragma unroll
    for (int s = 0; s < 4; s++){
        int yy = 2*py + (s >> 1), xxp = 2*px + (s & 1);
        int yxn = yy*IMW + xxp;
        int idx = yb ? imapP[(size_t)yxn*BATCH + b] : imapP[(size_t)b*HW + yxn];
        if (idx >= 0){
            const uint4* row = (const uint4*)(ws + OFF_COMPACT + (size_t)idx*128);
            #pragma unroll
            for (int q = 0; q < 8; q++){
                uint4 v = row[q];
                mx[q*8+0] = fmaxf(mx[q*8+0], bflo(v.x)); mx[q*8+1] = fmaxf(mx[q*8+1], bfhi(v.x));
                mx[q*8+2] = fmaxf(mx[q*8+2], bflo(v.y)); mx[q*8+3] = fmaxf(mx[q*8+3], bfhi(v.y));
                mx[q*8+4] = fmaxf(mx[q*8+4], bflo(v.z)); mx[q*8+5] = fmaxf(mx[q*8+5], bfhi(v.z));
                mx[q*8+6] = fmaxf(mx[q*8+6], bflo(v.w)); mx[q*8+7] = fmaxf(mx[q*8+7], bfhi(v.w));
            }
        }
    }
    uint16_t* pooled = (uint16_t*)(ws + OFF_POOLED);
    #pragma unroll
    for (int oc = 0; oc < 64; oc++)
        pooled[(size_t)(oc*NCELL + cell)*BATCH + b] = (uint16_t)f2bf(mx[oc]);
}

// ---------------- K5: fc1 GEMM partials (k-split x16, n-quarters x4) ---------------
__global__ __launch_bounds__(256) void fc1_k(uint8_t* __restrict__ ws){
    int gw   = (blockIdx.x * 256 + threadIdx.x) >> 6;
    int lane = threadIdx.x & 63;
    int bg = gw & 63, nq = (gw >> 6) & 3, kc = gw >> 8;   // 64 x 4 x 16 = 4096 waves
    int b = bg*64 + lane;
    const uint16_t* pooled = (const uint16_t*)(ws + OFF_POOLED);
    const float*    fc1t   = (const float*)(ws + OFF_FC1T);
    float acc[32];
    #pragma unroll
    for (int i = 0; i < 32; i++) acc[i] = 0.f;
    int k0 = kc * 784;
    for (int k = k0; k < k0 + 784; k++){
        float v = bfu16(pooled[(size_t)k*BATCH + b]);
        const float* wk = fc1t + (size_t)k*128 + nq*32;
        #pragma unroll
        for (int j = 0; j < 32; j++) acc[j] = fmaf(v, wk[j], acc[j]);
    }
    float* partial = (float*)(ws + OFF_PARTIAL);
    #pragma unroll
    for (int j = 0; j < 32; j++)
        partial[(size_t)(kc*128 + nq*32 + j)*BATCH + b] = acc[j];
}

// ---------------- K5b: reduce partials + bias + relu -> h3T[n][b] f32 --------------
__global__ __launch_bounds__(256) void fc1red_k(const void* __restrict__ fc1b,
                                                uint8_t* __restrict__ ws){
    int t = blockIdx.x * 256 + threadIdx.x;  // t = n*4096 + b
    int b = t & 4095; int n = t >> 12;
    int ifmt = *(volatile int*)(ws + OFF_IFMT);
    const float* partial = (const float*)(ws + OFF_PARTIAL);
    float s = ldin(fc1b, n, ifmt);
    #pragma unroll
    for (int kc = 0; kc < 16; kc++) s += partial[(size_t)(kc*128 + n)*BATCH + b];
    ((float*)(ws + OFF_H3))[t] = fmaxf(s, 0.f);
}

// ---------------- K6: fc2 + log_softmax -> out [B][10] f32 -------------------------
__global__ __launch_bounds__(256) void fc2_k(const void* __restrict__ fc2b,
                                             uint8_t* __restrict__ ws,
                                             float* __restrict__ out){
    int b = blockIdx.x * 256 + threadIdx.x;  // 4096 threads
    int ifmt = *(volatile int*)(ws + OFF_IFMT);
    const float* h3   = (const float*)(ws + OFF_H3);
    const float* fc2t = (const float*)(ws + OFF_FC2T);
    float acc[10];
    #pragma unroll
    for (int n = 0; n < 10; n++) acc[n] = ldin(fc2b, n, ifmt);
    for (int k = 0; k < 128; k++){
        float v = h3[(size_t)k*BATCH + b];
        const float* wk = fc2t + k*10;
        #pragma unroll
        for (int n = 0; n < 10; n++) acc[n] = fmaf(v, wk[n], acc[n]);
    }
    float m = acc[0];
    #pragma unroll
    for (int n = 1; n < 10; n++) m = fmaxf(m, acc[n]);
    float s = 0.f;
    #pragma unroll
    for (int n = 0; n < 10; n++) s += expf(acc[n] - m);
    float ls = logf(s);
    #pragma unroll
    for (int n = 0; n < 10; n++) out[(size_t)b*10 + n] = acc[n] - m - ls;
}

extern "C" void kernel_launch(void* const* d_in, const int* in_sizes, int n_in,
                              void* d_out, int out_size, void* d_ws, size_t ws_size,
                              hipStream_t stream){
    const void* x    = d_in[0];
    const void* mask = d_in[1];
    const void* w1   = d_in[2];
    const void* w2   = d_in[3];
    const void* fc1w = d_in[4];
    const void* fc1b = d_in[5];
    const void* fc2w = d_in[6];
    const void* fc2b = d_in[7];
    uint8_t* ws = (uint8_t*)d_ws;
    float* out = (float*)d_out;

    bool has_yb = ws_size >= (OFF_IDXYB + (12ull<<20) + (1ull<<20));
    int* idx_yb = (int*)(ws + OFF_IDXYB);
    const int* pool_imap = has_yb ? idx_yb : (const int*)(ws + OFF_IDX);

    hipLaunchKernelGGL(probe_k,   dim3(1),          dim3(256), 0, stream, mask, fc1w, ws);
    hipLaunchKernelGGL(prep_k,    dim3(72),         dim3(256), 0, stream, w1, w2, fc2w, ws);
    hipLaunchKernelGGL(fc1t_k,    dim3(784, 8),     dim3(256), 0, stream, fc1w, ws);
    hipLaunchKernelGGL(compact_k, dim3(12544),      dim3(256), 0, stream, mask, ws);
    if (has_yb)
        hipLaunchKernelGGL(idxT_k, dim3(49, 256),   dim3(256), 0, stream, ws, idx_yb);
    hipLaunchKernelGGL(conv1_k,   dim3(2560),       dim3(256), 0, stream, x, ws);
    hipLaunchKernelGGL(conv2_k,   dim3(2560),       dim3(256), 0, stream, ws);
    hipLaunchKernelGGL(pool_k,    dim3(3136),       dim3(256), 0, stream, ws, pool_imap, has_yb ? 1 : 0);
    hipLaunchKernelGGL(fc1_k,     dim3(1024),       dim3(256), 0, stream, ws);
    hipLaunchKernelGGL(fc1red_k,  dim3(2048),       dim3(256), 0, stream, fc1b, ws);
    hipLaunchKernelGGL(fc2_k,     dim3(16),         dim3(256), 0, stream, fc2b, ws, out);
}

// Round 7
// 1730.786 us; speedup vs baseline: 1.7888x; 1.3910x over previous
//
#include <hip/hip_runtime.h>
#include <hip/hip_bf16.h>
#include <stdint.h>

// Problem constants
#define BATCH 4096
#define HW 784          // 28*28
#define IMW 28
#define NCELL 196       // 14*14
#define K_FC 12544
#define LMAX 655360     // active-site list capacity (expected ~642,253 = mean+18sigma)

// Workspace layout (bytes). Base peak 204 MiB (known to fit); IDX_YB (12.25 MiB)
// appended at 204M only if ws_size allows, else pool falls back to strided reads.
#define OFF_FLAG    0ull               // mask storage format
#define OFF_CNT     4ull               // active-site counter
#define OFF_IFMT    8ull               // input float format: 0=f32, 1=bf16
#define OFF_W1T     1024ull            // f32[9][32]        1152 B
#define OFF_W2T     4096ull            // f32[9][32][64]    73728 B (ends 77824)
#define OFF_FC2T    81920ull           // f32[128][10]      5120 B
#define OFF_H3      (512ull<<10)       // f32[128][4096]    2 MiB (ends 2.5M)
#define OFF_FC1T    (3ull<<20)         // f32[12544][128]   6.125 MiB (ends 9.125M)
#define OFF_IDX     (10ull<<20)        // i32[4096][784]  (b-major) 12.25 MiB (ends 22.25M)
#define OFF_LIST    (23ull<<20)        // u32[LMAX]         2.5 MiB (ends 25.5M)
#define OFF_COMPACT (26ull<<20)        // bf16[LMAX][64]    80 MiB (ends 106M)
#define OFF_PARTIAL (26ull<<20)        // f32[16*128][4096] 32 MiB — aliases COMPACT (dead by then)
#define OFF_H1C     (106ull<<20)       // bf16[LMAX][32]    40 MiB (ends 146M)
#define OFF_POOLED  (106ull<<20)       // bf16[12544][4096] 98 MiB — aliases H1C (dead), ends 204M
#define OFF_IDXYB   (204ull<<20)       // i32[784][4096]  (yx-major, for pool) 12.25 MiB if room

__device__ __forceinline__ float bflo(uint32_t u){ return __uint_as_float(u << 16); }
__device__ __forceinline__ float bfhi(uint32_t u){ return __uint_as_float(u & 0xFFFF0000u); }
__device__ __forceinline__ float bfu16(uint16_t h){ return __uint_as_float(((uint32_t)h) << 16); }
__device__ __forceinline__ uint32_t f2bf(float f){
    uint32_t u = __float_as_uint(f);
    return (u + 0x7FFFu + ((u >> 16) & 1u)) >> 16;   // RNE
}
__device__ __forceinline__ uint32_t packbf(float a, float b){
    return f2bf(a) | (f2bf(b) << 16);
}

// Input float tensor load honoring probed storage format (0=f32, 1=bf16)
__device__ __forceinline__ float ldin(const void* p, size_t i, int ifmt){
    return ifmt ? bfu16(((const uint16_t*)p)[i]) : ((const float*)p)[i];
}

// mask storage: 0 = u8 bytes, 1 = int32, 2 = f32 (0/1.0f), 3 = bf16 (0/0x3F80)
__device__ __forceinline__ bool mask_active(const void* mp, int pix, int flag){
    if (flag == 1) return ((const int*)mp)[pix] != 0;
    if (flag == 0) return ((const uint8_t*)mp)[pix] != 0;
    if (flag == 2) return ((const uint32_t*)mp)[pix] != 0u;
    return ((const uint16_t*)mp)[pix] != 0;
}

// ---------------- P0: probes (mask format, input float format), CNT=0 --------------
__global__ __launch_bounds__(256) void probe_k(const void* __restrict__ mask,
                                               const void* __restrict__ fc1w,
                                               uint8_t* __restrict__ ws){
    __shared__ int s_gt1, s_byte, s_f32, s_half, s_bad;
    if (threadIdx.x == 0){ s_gt1=0; s_byte=0; s_f32=0; s_half=0; s_bad=0;
                           *(int*)(ws + OFF_CNT) = 0; }
    __syncthreads();
    const uint32_t* mw = (const uint32_t*)mask;
    int gt1 = 0, bbyte = 0, bf32 = 0, bhalf = 0;
    for (int i = threadIdx.x; i < 16384; i += 256){
        uint32_t w = mw[i];
        if (w > 1u) gt1 = 1;
        uint32_t b0 = w & 0xFFu, b1 = (w>>8)&0xFFu, b2 = (w>>16)&0xFFu, b3 = w>>24;
        if (b0>1u || b1>1u || b2>1u || b3>1u) bbyte = 1;
        if (w != 0u && w != 0x3F800000u) bf32 = 1;
        uint32_t h0 = w & 0xFFFFu, h1 = w >> 16;
        if ((h0 != 0u && h0 != 0x3F80u) || (h1 != 0u && h1 != 0x3F80u)) bhalf = 1;
    }
    if (gt1)   atomicOr(&s_gt1, 1);
    if (bbyte) atomicOr(&s_byte, 1);
    if (bf32)  atomicOr(&s_f32, 1);
    if (bhalf) atomicOr(&s_half, 1);

    const uint32_t* fw = (const uint32_t*)fc1w;
    int bad = 0;
    for (int i = threadIdx.x; i < 4096; i += 256){
        uint32_t w = fw[i];
        uint32_t h0 = w & 0xFFFFu, h1 = w >> 16;
        uint32_t e0 = (h0 >> 7) & 0xFFu, e1 = (h1 >> 7) & 0xFFu;
        if (h0 != 0u && (e0 >= 0xF0u || e0 < 0x5Eu)) bad++;
        if (h1 != 0u && (e1 >= 0xF0u || e1 < 0x5Eu)) bad++;
    }
    if (bad) atomicAdd(&s_bad, bad);
    __syncthreads();
    if (threadIdx.x == 0){
        int flag;
        if      (!s_gt1)  flag = 1;
        else if (!s_byte) flag = 0;
        else if (!s_f32)  flag = 2;
        else if (!s_half) flag = 3;
        else              flag = 0;
        *(int*)(ws + OFF_FLAG) = flag;
        *(int*)(ws + OFF_IFMT) = (s_bad < 400) ? 1 : 0;
    }
}

// ---------------- P1: small weight transposes (w1, w2, fc2) ------------------------
__global__ __launch_bounds__(256) void prep_k(const void* __restrict__ w1,
                                              const void* __restrict__ w2,
                                              const void* __restrict__ fc2w,
                                              uint8_t* __restrict__ ws){
    int t = blockIdx.x * 256 + threadIdx.x;
    int ifmt = *(volatile int*)(ws + OFF_IFMT);
    float* w1t  = (float*)(ws + OFF_W1T);
    float* w2t  = (float*)(ws + OFF_W2T);
    float* fc2t = (float*)(ws + OFF_FC2T);
    if (t < 288){                       // W1T[tap][oc] <- W1[oc][0][tap]
        int tap = t >> 5, oc = t & 31;
        w1t[t] = ldin(w1, oc*9 + tap, ifmt);
    }
    if (t < 18432){                     // W2T[tap][ic][oc] <- W2[oc][ic][tap]
        int oc = t & 63, ic = (t >> 6) & 31, tap = t >> 11;
        w2t[t] = ldin(w2, (oc*32 + ic)*9 + tap, ifmt);
    }
    if (t < 1280){                      // FC2T[k][n] <- fc2w[n][k]
        int k = t / 10, n = t - k*10;
        fc2t[t] = ldin(fc2w, n*128 + k, ifmt);
    }
}

// ---------------- P2: fc1w transpose via LDS tiles: [128][12544] -> [12544][128] ---
__global__ __launch_bounds__(256) void fc1t_k(const void* __restrict__ fc1w,
                                              uint8_t* __restrict__ ws){
    __shared__ float tile[16][17];
    int ifmt = *(volatile int*)(ws + OFF_IFMT);
    int tx = threadIdx.x & 15, ty = threadIdx.x >> 4;
    int k0 = blockIdx.x * 16;           // 784 blocks over k
    int n0 = blockIdx.y * 16;           // 8 blocks over n
    tile[ty][tx] = ldin(fc1w, (size_t)(n0 + ty)*K_FC + (k0 + tx), ifmt);
    __syncthreads();
    float* fc1t = (float*)(ws + OFF_FC1T);
    fc1t[(size_t)(k0 + ty)*128 + (n0 + tx)] = tile[tx][ty];
}

// ---------------- K1: block-aggregated compaction -> CNT, LIST, IDX ----------------
__global__ __launch_bounds__(256) void compact_k(const void* __restrict__ mask,
                                                 uint8_t* __restrict__ ws){
    int t = blockIdx.x * 256 + threadIdx.x;            // pixel id = b*784 + yx
    int flag = *(volatile int*)(ws + OFF_FLAG);
    int b = t / HW; int yx = t - b*HW;
    bool act = mask_active(mask, t, flag);

    unsigned long long ball = __ballot(act);
    int lane = threadIdx.x & 63;
    int wid  = threadIdx.x >> 6;
    __shared__ int wbase[4];
    int wtot = __popcll(ball);
    if (lane == 0) wbase[wid] = wtot;
    __syncthreads();
    if (threadIdx.x == 0){
        int s0 = wbase[0], s1 = wbase[1], s2 = wbase[2], s3 = wbase[3];
        int base = atomicAdd((int*)(ws + OFF_CNT), s0 + s1 + s2 + s3);
        wbase[0] = base;
        wbase[1] = base + s0;
        wbase[2] = base + s0 + s1;
        wbase[3] = base + s0 + s1 + s2;
    }
    __syncthreads();

    int idx = -1;
    if (act){
        int pos = wbase[wid] + __popcll(ball & ((1ull << lane) - 1ull));
        if (pos < LMAX){
            ((uint32_t*)(ws + OFF_LIST))[pos] = ((uint32_t)yx << 12) | (uint32_t)b;
            idx = pos;
        }
    }
    ((int*)(ws + OFF_IDX))[t] = idx;    // [b][yx], coalesced
}

// ---------------- K1b: transpose IDX_BY [b][yx] -> IDX_YB [yx][b] for pool ---------
__global__ __launch_bounds__(256) void idxT_k(uint8_t* __restrict__ ws, int* __restrict__ dst){
    __shared__ int tile[16][17];
    int tx = threadIdx.x & 15, ty = threadIdx.x >> 4;
    int yx0 = blockIdx.x * 16;          // 49 blocks over yx
    int b0  = blockIdx.y * 16;          // 256 blocks over b
    const int* src = (const int*)(ws + OFF_IDX);
    tile[ty][tx] = src[(size_t)(b0 + ty)*HW + (yx0 + tx)];
    __syncthreads();
    dst[(size_t)(yx0 + ty)*BATCH + (b0 + tx)] = tile[tx][ty];
}

// ---------------- K2: conv1 (1->32) + relu at active sites -> H1C bf16 -------------
__global__ __launch_bounds__(256) void conv1_k(const void* __restrict__ x,
                                               uint8_t* __restrict__ ws){
    int e = blockIdx.x * 256 + threadIdx.x;
    int count = *(volatile int*)(ws + OFF_CNT);
    if (count > LMAX) count = LMAX;
    if (e >= count) return;
    int ifmt = *(volatile int*)(ws + OFF_IFMT);
    const float* w1t = (const float*)(ws + OFF_W1T);
    uint32_t code = ((const uint32_t*)(ws + OFF_LIST))[e];
    int b = code & 4095; int yx = code >> 12;
    int y = yx / IMW; int xx = yx - y*IMW;

    float acc[32];
    #pragma unroll
    for (int i = 0; i < 32; i++) acc[i] = 0.f;
    #pragma unroll
    for (int ky = 0; ky < 3; ky++){
        #pragma unroll
        for (int kx = 0; kx < 3; kx++){
            int ny = y + ky - 1, nx = xx + kx - 1;
            bool inb = ((unsigned)ny < 28u) && ((unsigned)nx < 28u);
            float xv = inb ? ldin(x, (size_t)b*HW + ny*IMW + nx, ifmt) : 0.f;
            const float* wt = w1t + (ky*3 + kx)*32;
            #pragma unroll
            for (int oc = 0; oc < 32; oc++) acc[oc] = fmaf(xv, wt[oc], acc[oc]);
        }
    }
    uint32_t o[16];
    #pragma unroll
    for (int i = 0; i < 16; i++)
        o[i] = packbf(fmaxf(acc[2*i], 0.f), fmaxf(acc[2*i+1], 0.f));
    uint4* dst = (uint4*)(ws + OFF_H1C + (size_t)e*64);
    dst[0] = make_uint4(o[0],o[1],o[2],o[3]);
    dst[1] = make_uint4(o[4],o[5],o[6],o[7]);
    dst[2] = make_uint4(o[8],o[9],o[10],o[11]);
    dst[3] = make_uint4(o[12],o[13],o[14],o[15]);
}

// ---------------- K3: conv2 (32->64) at active sites, fused oc, coalesced imap -----
__global__ __launch_bounds__(256) void conv2_k(uint8_t* __restrict__ ws){
    int e = blockIdx.x * 256 + threadIdx.x;
    int count = *(volatile int*)(ws + OFF_CNT);
    if (count > LMAX) count = LMAX;
    if (e >= count) return;
    const float*    w2t  = (const float*)(ws + OFF_W2T);
    const uint32_t* h1c  = (const uint32_t*)(ws + OFF_H1C);
    const int*      imap = (const int*)(ws + OFF_IDX);   // [b][yx]
    uint32_t code = ((const uint32_t*)(ws + OFF_LIST))[e];
    int b = code & 4095; int yx = code >> 12;
    int y = yx / IMW; int xx = yx - y*IMW;
    const int* imb = imap + (size_t)b*HW;

    int nidx[9];
    #pragma unroll
    for (int tap = 0; tap < 9; tap++){
        int dy = tap/3 - 1, dx = tap - (tap/3)*3 - 1;
        int ny = y + dy, nx = xx + dx;
        bool inb = ((unsigned)ny < 28u) && ((unsigned)nx < 28u);
        nidx[tap] = inb ? imb[ny*IMW + nx] : -1;
    }

    float acc[64];
    #pragma unroll
    for (int i = 0; i < 64; i++) acc[i] = 0.f;
    for (int tap = 0; tap < 9; tap++){
        int ni = nidx[tap];
        uint32_t hv[16];
        if (ni >= 0){
            const uint4* q = (const uint4*)(h1c + (size_t)ni*16);
            uint4 a = q[0], c = q[1], d = q[2], f = q[3];
            hv[0]=a.x; hv[1]=a.y; hv[2]=a.z; hv[3]=a.w;
            hv[4]=c.x; hv[5]=c.y; hv[6]=c.z; hv[7]=c.w;
            hv[8]=d.x; hv[9]=d.y; hv[10]=d.z; hv[11]=d.w;
            hv[12]=f.x; hv[13]=f.y; hv[14]=f.z; hv[15]=f.w;
        } else {
            #pragma unroll
            for (int i = 0; i < 16; i++) hv[i] = 0u;
        }
        const float* wt = w2t + tap*2048;
        #pragma unroll 4
        for (int icp = 0; icp < 16; icp++){
            float v0 = bflo(hv[icp]), v1 = bfhi(hv[icp]);
            const float* wa = wt + (2*icp)*64;
            const float* wb = wa + 64;
            #pragma unroll
            for (int oc = 0; oc < 64; oc++){
                acc[oc] = fmaf(v0, wa[oc], acc[oc]);
                acc[oc] = fmaf(v1, wb[oc], acc[oc]);
            }
        }
    }
    uint32_t o[32];
    #pragma unroll
    for (int i = 0; i < 32; i++)
        o[i] = packbf(fmaxf(acc[2*i], 0.f), fmaxf(acc[2*i+1], 0.f));
    uint4* dst = (uint4*)(ws + OFF_COMPACT + (size_t)e*128);
    #pragma unroll
    for (int q = 0; q < 8; q++)
        dst[q] = make_uint4(o[4*q], o[4*q+1], o[4*q+2], o[4*q+3]);
}

// ---------------- K4: maxpool 2x2 -> pooledT[k=oc*196+cell][b] bf16 ----------------
__global__ __launch_bounds__(256) void pool_k(uint8_t* __restrict__ ws,
                                              const int* __restrict__ imapP, int yb){
    int t = blockIdx.x * 256 + threadIdx.x;  // t = cell*4096 + b
    int b = t & 4095; int cell = t >> 12;
    int py = cell / 14, px = cell - py*14;
    float mx[64];
    #pragma unroll
    for (int i = 0; i < 64; i++) mx[i] = 0.f;
    #pragma unroll
    for (int s = 0; s < 4; s++){
        int yy = 2*py + (s >> 1), xxp = 2*px + (s & 1);
        int yxn = yy*IMW + xxp;
        int idx = yb ? imapP[(size_t)yxn*BATCH + b] : imapP[(size_t)b*HW + yxn];
        if (idx >= 0){
            const uint4* row = (const uint4*)(ws + OFF_COMPACT + (size_t)idx*128);
            #pragma unroll
            for (int q = 0; q < 8; q++){
                uint4 v = row[q];
                mx[q*8+0] = fmaxf(mx[q*8+0], bflo(v.x)); mx[q*8+1] = fmaxf(mx[q*8+1], bfhi(v.x));
                mx[q*8+2] = fmaxf(mx[q*8+2], bflo(v.y)); mx[q*8+3] = fmaxf(mx[q*8+3], bfhi(v.y));
                mx[q*8+4] = fmaxf(mx[q*8+4], bflo(v.z)); mx[q*8+5] = fmaxf(mx[q*8+5], bfhi(v.z));
                mx[q*8+6] = fmaxf(mx[q*8+6], bflo(v.w)); mx[q*8+7] = fmaxf(mx[q*8+7], bfhi(v.w));
            }
        }
    }
    uint16_t* pooled = (uint16_t*)(ws + OFF_POOLED);
    #pragma unroll
    for (int oc = 0; oc < 64; oc++)
        pooled[(size_t)(oc*NCELL + cell)*BATCH + b] = (uint16_t)f2bf(mx[oc]);
}

// ---------------- K5: fc1 GEMM partials (k-split x16, n-quarters x4) ---------------
__global__ __launch_bounds__(256) void fc1_k(uint8_t* __restrict__ ws){
    int gw   = (blockIdx.x * 256 + threadIdx.x) >> 6;
    int lane = threadIdx.x & 63;
    int bg = gw & 63, nq = (gw >> 6) & 3, kc = gw >> 8;   // 64 x 4 x 16 = 4096 waves
    int b = bg*64 + lane;
    const uint16_t* pooled = (const uint16_t*)(ws + OFF_POOLED);
    const float*    fc1t   = (const float*)(ws + OFF_FC1T);
    float acc[32];
    #pragma unroll
    for (int i = 0; i < 32; i++) acc[i] = 0.f;
    int k0 = kc * 784;
    for (int k = k0; k < k0 + 784; k++){
        float v = bfu16(pooled[(size_t)k*BATCH + b]);
        const float* wk = fc1t + (size_t)k*128 + nq*32;
        #pragma unroll
        for (int j = 0; j < 32; j++) acc[j] = fmaf(v, wk[j], acc[j]);
    }
    float* partial = (float*)(ws + OFF_PARTIAL);
    #pragma unroll
    for (int j = 0; j < 32; j++)
        partial[(size_t)(kc*128 + nq*32 + j)*BATCH + b] = acc[j];
}

// ---------------- K5b: reduce partials + bias + relu -> h3T[n][b] f32 --------------
__global__ __launch_bounds__(256) void fc1red_k(const void* __restrict__ fc1b,
                                                uint8_t* __restrict__ ws){
    int t = blockIdx.x * 256 + threadIdx.x;  // t = n*4096 + b
    int b = t & 4095; int n = t >> 12;
    int ifmt = *(volatile int*)(ws + OFF_IFMT);
    const float* partial = (const float*)(ws + OFF_PARTIAL);
    float s = ldin(fc1b, n, ifmt);
    #pragma unroll
    for (int kc = 0; kc < 16; kc++) s += partial[(size_t)(kc*128 + n)*BATCH + b];
    ((float*)(ws + OFF_H3))[t] = fmaxf(s, 0.f);
}

// ---------------- K6: fc2 + log_softmax -> out [B][10] f32 -------------------------
__global__ __launch_bounds__(256) void fc2_k(const void* __restrict__ fc2b,
                                             uint8_t* __restrict__ ws,
                                             float* __restrict__ out){
    int b = blockIdx.x * 256 + threadIdx.x;  // 4096 threads
    int ifmt = *(volatile int*)(ws + OFF_IFMT);
    const float* h3   = (const float*)(ws + OFF_H3);
    const float* fc2t = (const float*)(ws + OFF_FC2T);
    float acc[10];
    #pragma unroll
    for (int n = 0; n < 10; n++) acc[n] = ldin(fc2b, n, ifmt);
    for (int k = 0; k < 128; k++){
        float v = h3[(size_t)k*BATCH + b];
        const float* wk = fc2t + k*10;
        #pragma unroll
        for (int n = 0; n < 10; n++) acc[n] = fmaf(v, wk[n], acc[n]);
    }
    float m = acc[0];
    #pragma unroll
    for (int n = 1; n < 10; n++) m = fmaxf(m, acc[n]);
    float s = 0.f;
    #pragma unroll
    for (int n = 0; n < 10; n++) s += expf(acc[n] - m);
    float ls = logf(s);
    #pragma unroll
    for (int n = 0; n < 10; n++) out[(size_t)b*10 + n] = acc[n] - m - ls;
}

extern "C" void kernel_launch(void* const* d_in, const int* in_sizes, int n_in,
                              void* d_out, int out_size, void* d_ws, size_t ws_size,
                              hipStream_t stream){
    const void* x    = d_in[0];
    const void* mask = d_in[1];
    const void* w1   = d_in[2];
    const void* w2   = d_in[3];
    const void* fc1w = d_in[4];
    const void* fc1b = d_in[5];
    const void* fc2w = d_in[6];
    const void* fc2b = d_in[7];
    uint8_t* ws = (uint8_t*)d_ws;
    float* out = (float*)d_out;

    bool has_yb = ws_size >= (OFF_IDXYB + (12ull<<20) + (1ull<<20));
    int* idx_yb = (int*)(ws + OFF_IDXYB);
    const int* pool_imap = has_yb ? idx_yb : (const int*)(ws + OFF_IDX);

    hipLaunchKernelGGL(probe_k,   dim3(1),          dim3(256), 0, stream, mask, fc1w, ws);
    hipLaunchKernelGGL(prep_k,    dim3(72),         dim3(256), 0, stream, w1, w2, fc2w, ws);
    hipLaunchKernelGGL(fc1t_k,    dim3(784, 8),     dim3(256), 0, stream, fc1w, ws);
    hipLaunchKernelGGL(compact_k, dim3(12544),      dim3(256), 0, stream, mask, ws);
    if (has_yb)
        hipLaunchKernelGGL(idxT_k, dim3(49, 256),   dim3(256), 0, stream, ws, idx_yb);
    hipLaunchKernelGGL(conv1_k,   dim3(2560),       dim3(256), 0, stream, x, ws);
    hipLaunchKernelGGL(conv2_k,   dim3(2560),       dim3(256), 0, stream, ws);
    hipLaunchKernelGGL(pool_k,    dim3(3136),       dim3(256), 0, stream, ws, pool_imap, has_yb ? 1 : 0);
    hipLaunchKernelGGL(fc1_k,     dim3(1024),       dim3(256), 0, stream, ws);
    hipLaunchKernelGGL(fc1red_k,  dim3(2048),       dim3(256), 0, stream, fc1b, ws);
    hipLaunchKernelGGL(fc2_k,     dim3(16),         dim3(256), 0, stream, fc2b, ws, out);
}

// Round 8
// 1063.945 us; speedup vs baseline: 2.9100x; 1.6268x over previous
//
#include <hip/hip_runtime.h>
#include <hip/hip_bf16.h>
#include <stdint.h>

// Problem constants
#define BATCH 4096
#define HW 784          // 28*28
#define IMW 28
#define NCELL 196       // 14*14
#define K_FC 12544
#define LMAX 655360     // active-site list capacity (expected ~642,253 = mean+18sigma)

// Workspace layout (bytes). Peak 204 MiB (known to fit).
#define OFF_FLAG    0ull               // mask storage format
#define OFF_CNT     4ull               // active-site counter
#define OFF_IFMT    8ull               // input float format: 0=f32, 1=bf16
#define OFF_W1T     1024ull            // f32[9][32]        1152 B
#define OFF_W2T     4096ull            // f32[9][32][64]    73728 B (ends 77824)
#define OFF_FC2T    81920ull           // f32[128][10]      5120 B
#define OFF_H3      (512ull<<10)       // f32[128][4096]    2 MiB (ends 2.5M)
#define OFF_FC1WB   (3ull<<20)         // bf16[128][12544]  3.06 MiB (ends 6.2M)
#define OFF_IDX     (10ull<<20)        // i32[4096][784]  (b-major) 12.25 MiB (ends 22.25M)
#define OFF_LIST    (23ull<<20)        // u32[LMAX]         2.5 MiB (ends 25.5M)
#define OFF_COMPACT (26ull<<20)        // bf16[LMAX][64]    80 MiB (ends 106M)
#define OFF_PARTIAL (26ull<<20)        // f32[4][128][4096] 8 MiB — aliases COMPACT (dead by then)
#define OFF_H1C     (106ull<<20)       // bf16[LMAX][32]    40 MiB (ends 146M)
#define OFF_POOLED  (106ull<<20)       // bf16[4096][12544] (b-major!) 98 MiB — aliases H1C (dead), ends 204M

typedef short bf16x8 __attribute__((ext_vector_type(8)));   // 8 bf16 (4 VGPRs), per guide §3
typedef float f32x4  __attribute__((ext_vector_type(4)));

__device__ __forceinline__ float bflo(uint32_t u){ return __uint_as_float(u << 16); }
__device__ __forceinline__ float bfhi(uint32_t u){ return __uint_as_float(u & 0xFFFF0000u); }
__device__ __forceinline__ float bfu16(uint16_t h){ return __uint_as_float(((uint32_t)h) << 16); }
__device__ __forceinline__ uint32_t f2bf(float f){
    uint32_t u = __float_as_uint(f);
    return (u + 0x7FFFu + ((u >> 16) & 1u)) >> 16;   // RNE
}
__device__ __forceinline__ uint32_t packbf(float a, float b){
    return f2bf(a) | (f2bf(b) << 16);
}

// Input float tensor load honoring probed storage format (0=f32, 1=bf16)
__device__ __forceinline__ float ldin(const void* p, size_t i, int ifmt){
    return ifmt ? bfu16(((const uint16_t*)p)[i]) : ((const float*)p)[i];
}

// mask storage: 0 = u8 bytes, 1 = int32, 2 = f32 (0/1.0f), 3 = bf16 (0/0x3F80)
__device__ __forceinline__ bool mask_active(const void* mp, int pix, int flag){
    if (flag == 1) return ((const int*)mp)[pix] != 0;
    if (flag == 0) return ((const uint8_t*)mp)[pix] != 0;
    if (flag == 2) return ((const uint32_t*)mp)[pix] != 0u;
    return ((const uint16_t*)mp)[pix] != 0;
}

// ---------------- P0: probes (mask format, input float format), CNT=0 --------------
__global__ __launch_bounds__(256) void probe_k(const void* __restrict__ mask,
                                               const void* __restrict__ fc1w,
                                               uint8_t* __restrict__ ws){
    __shared__ int s_gt1, s_byte, s_f32, s_half, s_bad;
    if (threadIdx.x == 0){ s_gt1=0; s_byte=0; s_f32=0; s_half=0; s_bad=0;
                           *(int*)(ws + OFF_CNT) = 0; }
    __syncthreads();
    const uint32_t* mw = (const uint32_t*)mask;
    int gt1 = 0, bbyte = 0, bf32 = 0, bhalf = 0;
    for (int i = threadIdx.x; i < 16384; i += 256){
        uint32_t w = mw[i];
        if (w > 1u) gt1 = 1;
        uint32_t b0 = w & 0xFFu, b1 = (w>>8)&0xFFu, b2 = (w>>16)&0xFFu, b3 = w>>24;
        if (b0>1u || b1>1u || b2>1u || b3>1u) bbyte = 1;
        if (w != 0u && w != 0x3F800000u) bf32 = 1;
        uint32_t h0 = w & 0xFFFFu, h1 = w >> 16;
        if ((h0 != 0u && h0 != 0x3F80u) || (h1 != 0u && h1 != 0x3F80u)) bhalf = 1;
    }
    if (gt1)   atomicOr(&s_gt1, 1);
    if (bbyte) atomicOr(&s_byte, 1);
    if (bf32)  atomicOr(&s_f32, 1);
    if (bhalf) atomicOr(&s_half, 1);

    const uint32_t* fw = (const uint32_t*)fc1w;
    int bad = 0;
    for (int i = threadIdx.x; i < 4096; i += 256){
        uint32_t w = fw[i];
        uint32_t h0 = w & 0xFFFFu, h1 = w >> 16;
        uint32_t e0 = (h0 >> 7) & 0xFFu, e1 = (h1 >> 7) & 0xFFu;
        if (h0 != 0u && (e0 >= 0xF0u || e0 < 0x5Eu)) bad++;
        if (h1 != 0u && (e1 >= 0xF0u || e1 < 0x5Eu)) bad++;
    }
    if (bad) atomicAdd(&s_bad, bad);
    __syncthreads();
    if (threadIdx.x == 0){
        int flag;
        if      (!s_gt1)  flag = 1;
        else if (!s_byte) flag = 0;
        else if (!s_f32)  flag = 2;
        else if (!s_half) flag = 3;
        else              flag = 0;
        *(int*)(ws + OFF_FLAG) = flag;
        *(int*)(ws + OFF_IFMT) = (s_bad < 400) ? 1 : 0;
    }
}

// ---------------- P1: small weight transposes (w1, w2, fc2) ------------------------
__global__ __launch_bounds__(256) void prep_k(const void* __restrict__ w1,
                                              const void* __restrict__ w2,
                                              const void* __restrict__ fc2w,
                                              uint8_t* __restrict__ ws){
    int t = blockIdx.x * 256 + threadIdx.x;
    int ifmt = *(volatile int*)(ws + OFF_IFMT);
    float* w1t  = (float*)(ws + OFF_W1T);
    float* w2t  = (float*)(ws + OFF_W2T);
    float* fc2t = (float*)(ws + OFF_FC2T);
    if (t < 288){                       // W1T[tap][oc] <- W1[oc][0][tap]
        int tap = t >> 5, oc = t & 31;
        w1t[t] = ldin(w1, oc*9 + tap, ifmt);
    }
    if (t < 18432){                     // W2T[tap][ic][oc] <- W2[oc][ic][tap]
        int oc = t & 63, ic = (t >> 6) & 31, tap = t >> 11;
        w2t[t] = ldin(w2, (oc*32 + ic)*9 + tap, ifmt);
    }
    if (t < 1280){                      // FC2T[k][n] <- fc2w[n][k]
        int k = t / 10, n = t - k*10;
        fc2t[t] = ldin(fc2w, n*128 + k, ifmt);
    }
}

// ---------------- P2: fc1w -> bf16 [128][12544] (k-contiguous, for MFMA A-frag) ----
__global__ __launch_bounds__(256) void fc1wb_k(const void* __restrict__ fc1w,
                                               uint8_t* __restrict__ ws){
    int t = blockIdx.x * 256 + threadIdx.x;   // 6272*256 == 1605632 exactly
    int ifmt = *(volatile int*)(ws + OFF_IFMT);
    ((uint16_t*)(ws + OFF_FC1WB))[t] = (uint16_t)f2bf(ldin(fc1w, t, ifmt));
}

// ---------------- K1: block-aggregated compaction -> CNT, LIST, IDX ----------------
__global__ __launch_bounds__(256) void compact_k(const void* __restrict__ mask,
                                                 uint8_t* __restrict__ ws){
    int t = blockIdx.x * 256 + threadIdx.x;            // pixel id = b*784 + yx
    int flag = *(volatile int*)(ws + OFF_FLAG);
    int b = t / HW; int yx = t - b*HW;
    bool act = mask_active(mask, t, flag);

    unsigned long long ball = __ballot(act);
    int lane = threadIdx.x & 63;
    int wid  = threadIdx.x >> 6;
    __shared__ int wbase[4];
    int wtot = __popcll(ball);
    if (lane == 0) wbase[wid] = wtot;
    __syncthreads();
    if (threadIdx.x == 0){
        int s0 = wbase[0], s1 = wbase[1], s2 = wbase[2], s3 = wbase[3];
        int base = atomicAdd((int*)(ws + OFF_CNT), s0 + s1 + s2 + s3);
        wbase[0] = base;
        wbase[1] = base + s0;
        wbase[2] = base + s0 + s1;
        wbase[3] = base + s0 + s1 + s2;
    }
    __syncthreads();

    int idx = -1;
    if (act){
        int pos = wbase[wid] + __popcll(ball & ((1ull << lane) - 1ull));
        if (pos < LMAX){
            ((uint32_t*)(ws + OFF_LIST))[pos] = ((uint32_t)yx << 12) | (uint32_t)b;
            idx = pos;
        }
    }
    ((int*)(ws + OFF_IDX))[t] = idx;    // [b][yx], coalesced
}

// ---------------- K2: conv1 (1->32) + relu at active sites -> H1C bf16 -------------
__global__ __launch_bounds__(256) void conv1_k(const void* __restrict__ x,
                                               uint8_t* __restrict__ ws){
    int e = blockIdx.x * 256 + threadIdx.x;
    int count = *(volatile int*)(ws + OFF_CNT);
    if (count > LMAX) count = LMAX;
    if (e >= count) return;
    int ifmt = *(volatile int*)(ws + OFF_IFMT);
    const float* w1t = (const float*)(ws + OFF_W1T);
    uint32_t code = ((const uint32_t*)(ws + OFF_LIST))[e];
    int b = code & 4095; int yx = code >> 12;
    int y = yx / IMW; int xx = yx - y*IMW;

    float acc[32];
    #pragma unroll
    for (int i = 0; i < 32; i++) acc[i] = 0.f;
    #pragma unroll
    for (int ky = 0; ky < 3; ky++){
        #pragma unroll
        for (int kx = 0; kx < 3; kx++){
            int ny = y + ky - 1, nx = xx + kx - 1;
            bool inb = ((unsigned)ny < 28u) && ((unsigned)nx < 28u);
            float xv = inb ? ldin(x, (size_t)b*HW + ny*IMW + nx, ifmt) : 0.f;
            const float* wt = w1t + (ky*3 + kx)*32;
            #pragma unroll
            for (int oc = 0; oc < 32; oc++) acc[oc] = fmaf(xv, wt[oc], acc[oc]);
        }
    }
    uint32_t o[16];
    #pragma unroll
    for (int i = 0; i < 16; i++)
        o[i] = packbf(fmaxf(acc[2*i], 0.f), fmaxf(acc[2*i+1], 0.f));
    uint4* dst = (uint4*)(ws + OFF_H1C + (size_t)e*64);
    dst[0] = make_uint4(o[0],o[1],o[2],o[3]);
    dst[1] = make_uint4(o[4],o[5],o[6],o[7]);
    dst[2] = make_uint4(o[8],o[9],o[10],o[11]);
    dst[3] = make_uint4(o[12],o[13],o[14],o[15]);
}

// ---------------- K3: conv2 (32->64) at active sites, fused oc, coalesced imap -----
__global__ __launch_bounds__(256) void conv2_k(uint8_t* __restrict__ ws){
    int e = blockIdx.x * 256 + threadIdx.x;
    int count = *(volatile int*)(ws + OFF_CNT);
    if (count > LMAX) count = LMAX;
    if (e >= count) return;
    const float*    w2t  = (const float*)(ws + OFF_W2T);
    const uint32_t* h1c  = (const uint32_t*)(ws + OFF_H1C);
    const int*      imap = (const int*)(ws + OFF_IDX);   // [b][yx]
    uint32_t code = ((const uint32_t*)(ws + OFF_LIST))[e];
    int b = code & 4095; int yx = code >> 12;
    int y = yx / IMW; int xx = yx - y*IMW;
    const int* imb = imap + (size_t)b*HW;

    int nidx[9];
    #pragma unroll
    for (int tap = 0; tap < 9; tap++){
        int dy = tap/3 - 1, dx = tap - (tap/3)*3 - 1;
        int ny = y + dy, nx = xx + dx;
        bool inb = ((unsigned)ny < 28u) && ((unsigned)nx < 28u);
        nidx[tap] = inb ? imb[ny*IMW + nx] : -1;
    }

    float acc[64];
    #pragma unroll
    for (int i = 0; i < 64; i++) acc[i] = 0.f;
    for (int tap = 0; tap < 9; tap++){
        int ni = nidx[tap];
        uint32_t hv[16];
        if (ni >= 0){
            const uint4* q = (const uint4*)(h1c + (size_t)ni*16);
            uint4 a = q[0], c = q[1], d = q[2], f = q[3];
            hv[0]=a.x; hv[1]=a.y; hv[2]=a.z; hv[3]=a.w;
            hv[4]=c.x; hv[5]=c.y; hv[6]=c.z; hv[7]=c.w;
            hv[8]=d.x; hv[9]=d.y; hv[10]=d.z; hv[11]=d.w;
            hv[12]=f.x; hv[13]=f.y; hv[14]=f.z; hv[15]=f.w;
        } else {
            #pragma unroll
            for (int i = 0; i < 16; i++) hv[i] = 0u;
        }
        const float* wt = w2t + tap*2048;
        #pragma unroll 4
        for (int icp = 0; icp < 16; icp++){
            float v0 = bflo(hv[icp]), v1 = bfhi(hv[icp]);
            const float* wa = wt + (2*icp)*64;
            const float* wb = wa + 64;
            #pragma unroll
            for (int oc = 0; oc < 64; oc++){
                acc[oc] = fmaf(v0, wa[oc], acc[oc]);
                acc[oc] = fmaf(v1, wb[oc], acc[oc]);
            }
        }
    }
    uint32_t o[32];
    #pragma unroll
    for (int i = 0; i < 32; i++)
        o[i] = packbf(fmaxf(acc[2*i], 0.f), fmaxf(acc[2*i+1], 0.f));
    uint4* dst = (uint4*)(ws + OFF_COMPACT + (size_t)e*128);
    #pragma unroll
    for (int q = 0; q < 8; q++)
        dst[q] = make_uint4(o[4*q], o[4*q+1], o[4*q+2], o[4*q+3]);
}

// ---------------- K4: maxpool 2x2 -> pooled[b][k=oc*196+cell] bf16 -----------------
// One block per image b; lane = cell (196 active of 256).
__global__ __launch_bounds__(256) void pool_k(uint8_t* __restrict__ ws){
    int b = blockIdx.x;
    int cell = threadIdx.x;
    if (cell >= NCELL) return;
    int py = cell / 14, px = cell - py*14;
    const int* imb = (const int*)(ws + OFF_IDX) + (size_t)b*HW;   // [b][yx]
    float mx[64];
    #pragma unroll
    for (int i = 0; i < 64; i++) mx[i] = 0.f;
    #pragma unroll
    for (int s = 0; s < 4; s++){
        int yy = 2*py + (s >> 1), xxp = 2*px + (s & 1);
        int idx = imb[yy*IMW + xxp];
        if (idx >= 0){
            const uint4* row = (const uint4*)(ws + OFF_COMPACT + (size_t)idx*128);
            #pragma unroll
            for (int q = 0; q < 8; q++){
                uint4 v = row[q];
                mx[q*8+0] = fmaxf(mx[q*8+0], bflo(v.x)); mx[q*8+1] = fmaxf(mx[q*8+1], bfhi(v.x));
                mx[q*8+2] = fmaxf(mx[q*8+2], bflo(v.y)); mx[q*8+3] = fmaxf(mx[q*8+3], bfhi(v.y));
                mx[q*8+4] = fmaxf(mx[q*8+4], bflo(v.z)); mx[q*8+5] = fmaxf(mx[q*8+5], bfhi(v.z));
                mx[q*8+6] = fmaxf(mx[q*8+6], bflo(v.w)); mx[q*8+7] = fmaxf(mx[q*8+7], bfhi(v.w));
            }
        }
    }
    uint16_t* prow = (uint16_t*)(ws + OFF_POOLED) + (size_t)b*K_FC;
    #pragma unroll
    for (int oc = 0; oc < 64; oc++)
        prow[oc*NCELL + cell] = (uint16_t)f2bf(mx[oc]);   // lanes consecutive -> coalesced
}

// ---------------- K5: fc1 MFMA GEMM: h3[n][b] = fc1wb[n][:] . pooled[b][:] ---------
// Grid 512 blocks: kz(4) x nt(2) x bt(64). Block = 4 waves, wave tile 32n x 32b.
__global__ __launch_bounds__(256) void fc1mfma_k(uint8_t* __restrict__ ws){
    int wid = threadIdx.x >> 6, lane = threadIdx.x & 63;
    int bidx = blockIdx.x;
    int kz = bidx >> 7;               // 0..3
    int rem = bidx & 127;
    int nt = rem >> 6;                // 0..1
    int bt = rem & 63;                // 0..63
    int n0 = nt*64 + (wid >> 1)*32;
    int b0 = bt*64 + (wid & 1)*32;
    int l15 = lane & 15;
    int kb  = (lane >> 4) * 8;

    const uint16_t* W = (const uint16_t*)(ws + OFF_FC1WB);
    const uint16_t* P = (const uint16_t*)(ws + OFF_POOLED);
    const uint16_t* wa0 = W + (size_t)(n0 + l15)*K_FC + kb;
    const uint16_t* wa1 = wa0 + (size_t)16*K_FC;
    const uint16_t* pb0 = P + (size_t)(b0 + l15)*K_FC + kb;
    const uint16_t* pb1 = pb0 + (size_t)16*K_FC;

    f32x4 acc00 = {0.f,0.f,0.f,0.f}, acc01 = acc00, acc10 = acc00, acc11 = acc00;
    int k0 = kz * 3136;
    for (int k = k0; k < k0 + 3136; k += 64){
        bf16x8 a0 = *(const bf16x8*)(wa0 + k);
        bf16x8 a1 = *(const bf16x8*)(wa1 + k);
        bf16x8 p0 = *(const bf16x8*)(pb0 + k);
        bf16x8 p1 = *(const bf16x8*)(pb1 + k);
        bf16x8 a0b = *(const bf16x8*)(wa0 + k + 32);
        bf16x8 a1b = *(const bf16x8*)(wa1 + k + 32);
        bf16x8 p0b = *(const bf16x8*)(pb0 + k + 32);
        bf16x8 p1b = *(const bf16x8*)(pb1 + k + 32);
        acc00 = __builtin_amdgcn_mfma_f32_16x16x32_bf16(a0, p0, acc00, 0, 0, 0);
        acc01 = __builtin_amdgcn_mfma_f32_16x16x32_bf16(a0, p1, acc01, 0, 0, 0);
        acc10 = __builtin_amdgcn_mfma_f32_16x16x32_bf16(a1, p0, acc10, 0, 0, 0);
        acc11 = __builtin_amdgcn_mfma_f32_16x16x32_bf16(a1, p1, acc11, 0, 0, 0);
        acc00 = __builtin_amdgcn_mfma_f32_16x16x32_bf16(a0b, p0b, acc00, 0, 0, 0);
        acc01 = __builtin_amdgcn_mfma_f32_16x16x32_bf16(a0b, p1b, acc01, 0, 0, 0);
        acc10 = __builtin_amdgcn_mfma_f32_16x16x32_bf16(a1b, p0b, acc10, 0, 0, 0);
        acc11 = __builtin_amdgcn_mfma_f32_16x16x32_bf16(a1b, p1b, acc11, 0, 0, 0);
    }

    // D layout: col = lane&15 (b-local), row = (lane>>4)*4 + r (n-local)
    float* partial = (float*)(ws + OFF_PARTIAL);
    int rl = (lane >> 4) * 4;
    #pragma unroll
    for (int r = 0; r < 4; r++){
        size_t rowA = (size_t)(kz*128 + n0 + rl + r)*BATCH;
        size_t rowB = (size_t)(kz*128 + n0 + 16 + rl + r)*BATCH;
        partial[rowA + b0 + l15]      = acc00[r];
        partial[rowA + b0 + 16 + l15] = acc01[r];
        partial[rowB + b0 + l15]      = acc10[r];
        partial[rowB + b0 + 16 + l15] = acc11[r];
    }
}

// ---------------- K5b: reduce 4 partials + bias + relu -> h3[n][b] f32 -------------
__global__ __launch_bounds__(256) void fc1red_k(const void* __restrict__ fc1b,
                                                uint8_t* __restrict__ ws){
    int t = blockIdx.x * 256 + threadIdx.x;  // t = n*4096 + b
    int b = t & 4095; int n = t >> 12;
    int ifmt = *(volatile int*)(ws + OFF_IFMT);
    const float* partial = (const float*)(ws + OFF_PARTIAL);
    float s = ldin(fc1b, n, ifmt);
    #pragma unroll
    for (int kc = 0; kc < 4; kc++) s += partial[(size_t)(kc*128 + n)*BATCH + b];
    ((float*)(ws + OFF_H3))[t] = fmaxf(s, 0.f);
}

// ---------------- K6: fc2 + log_softmax -> out [B][10] f32 -------------------------
__global__ __launch_bounds__(256) void fc2_k(const void* __restrict__ fc2b,
                                             uint8_t* __restrict__ ws,
                                             float* __restrict__ out){
    int b = blockIdx.x * 256 + threadIdx.x;  // 4096 threads
    int ifmt = *(volatile int*)(ws + OFF_IFMT);
    const float* h3   = (const float*)(ws + OFF_H3);
    const float* fc2t = (const float*)(ws + OFF_FC2T);
    float acc[10];
    #pragma unroll
    for (int n = 0; n < 10; n++) acc[n] = ldin(fc2b, n, ifmt);
    for (int k = 0; k < 128; k++){
        float v = h3[(size_t)k*BATCH + b];
        const float* wk = fc2t + k*10;
        #pragma unroll
        for (int n = 0; n < 10; n++) acc[n] = fmaf(v, wk[n], acc[n]);
    }
    float m = acc[0];
    #pragma unroll
    for (int n = 1; n < 10; n++) m = fmaxf(m, acc[n]);
    float s = 0.f;
    #pragma unroll
    for (int n = 0; n < 10; n++) s += expf(acc[n] - m);
    float ls = logf(s);
    #pragma unroll
    for (int n = 0; n < 10; n++) out[(size_t)b*10 + n] = acc[n] - m - ls;
}

extern "C" void kernel_launch(void* const* d_in, const int* in_sizes, int n_in,
                              void* d_out, int out_size, void* d_ws, size_t ws_size,
                              hipStream_t stream){
    const void* x    = d_in[0];
    const void* mask = d_in[1];
    const void* w1   = d_in[2];
    const void* w2   = d_in[3];
    const void* fc1w = d_in[4];
    const void* fc1b = d_in[5];
    const void* fc2w = d_in[6];
    const void* fc2b = d_in[7];
    uint8_t* ws = (uint8_t*)d_ws;
    float* out = (float*)d_out;

    hipLaunchKernelGGL(probe_k,    dim3(1),     dim3(256), 0, stream, mask, fc1w, ws);
    hipLaunchKernelGGL(prep_k,     dim3(72),    dim3(256), 0, stream, w1, w2, fc2w, ws);
    hipLaunchKernelGGL(fc1wb_k,    dim3(6272),  dim3(256), 0, stream, fc1w, ws);
    hipLaunchKernelGGL(compact_k,  dim3(12544), dim3(256), 0, stream, mask, ws);
    hipLaunchKernelGGL(conv1_k,    dim3(2560),  dim3(256), 0, stream, x, ws);
    hipLaunchKernelGGL(conv2_k,    dim3(2560),  dim3(256), 0, stream, ws);
    hipLaunchKernelGGL(pool_k,     dim3(4096),  dim3(256), 0, stream, ws);
    hipLaunchKernelGGL(fc1mfma_k,  dim3(512),   dim3(256), 0, stream, ws);
    hipLaunchKernelGGL(fc1red_k,   dim3(2048),  dim3(256), 0, stream, fc1b, ws);
    hipLaunchKernelGGL(fc2_k,      dim3(16),    dim3(256), 0, stream, fc2b, ws, out);
}

// Round 9
// 668.305 us; speedup vs baseline: 4.6328x; 1.5920x over previous
//
#include <hip/hip_runtime.h>
#include <hip/hip_bf16.h>
#include <stdint.h>

// Problem constants
#define BATCH 4096
#define HW 784          // 28*28
#define IMW 28
#define NCELL 196       // 14*14
#define K_FC 12544
#define LMAX 655360     // active-site list capacity (expected ~642,253 = mean+18sigma)
#define NBLK 12544      // compaction grid blocks (NPIX/256)

// Workspace layout (bytes). Peak 204 MiB (known to fit).
#define OFF_FLAG    0ull               // mask storage format
#define OFF_CNT     4ull               // active-site counter
#define OFF_IFMT    8ull               // input float format: 0=f32, 1=bf16
#define OFF_W1T     1024ull            // f32[9][32]        1152 B
#define OFF_W2T     4096ull            // f32[9][32][64]    73728 B (ends 77824)
#define OFF_FC2T    81920ull           // f32[128][10]      5120 B
#define OFF_H3      (512ull<<10)       // f32[128][4096]    2 MiB (ends 2.5M)
#define OFF_FC1WB   (3ull<<20)         // bf16[128][12544]  3.06 MiB (ends 6.2M)
#define OFF_BLKCNT  (7ull<<20)         // i32[NBLK]         49 KiB
#define OFF_BLKOFF  (8ull<<20)         // i32[NBLK]         49 KiB
#define OFF_IDX     (10ull<<20)        // i32[4096][784]  (b-major) 12.25 MiB (ends 22.25M)
#define OFF_LIST    (23ull<<20)        // u32[LMAX]         2.5 MiB (ends 25.5M)
#define OFF_COMPACT (26ull<<20)        // bf16[LMAX][64]    80 MiB (ends 106M)
#define OFF_PARTIAL (26ull<<20)        // f32[4][128][4096] 8 MiB — aliases COMPACT (dead by then)
#define OFF_H1C     (106ull<<20)       // bf16[LMAX][32]    40 MiB (ends 146M)
#define OFF_POOLED  (106ull<<20)       // bf16[4096][12544] (b-major) 98 MiB — aliases H1C (dead), ends 204M

typedef short bf16x8 __attribute__((ext_vector_type(8)));   // 8 bf16 (4 VGPRs)
typedef float f32x4  __attribute__((ext_vector_type(4)));

__device__ __forceinline__ float bflo(uint32_t u){ return __uint_as_float(u << 16); }
__device__ __forceinline__ float bfhi(uint32_t u){ return __uint_as_float(u & 0xFFFF0000u); }
__device__ __forceinline__ float bfu16(uint16_t h){ return __uint_as_float(((uint32_t)h) << 16); }
__device__ __forceinline__ uint32_t f2bf(float f){
    uint32_t u = __float_as_uint(f);
    return (u + 0x7FFFu + ((u >> 16) & 1u)) >> 16;   // RNE
}
__device__ __forceinline__ uint32_t packbf(float a, float b){
    return f2bf(a) | (f2bf(b) << 16);
}

// Input float tensor load honoring probed storage format (0=f32, 1=bf16)
__device__ __forceinline__ float ldin(const void* p, size_t i, int ifmt){
    return ifmt ? bfu16(((const uint16_t*)p)[i]) : ((const float*)p)[i];
}

// mask storage: 0 = u8 bytes, 1 = int32, 2 = f32 (0/1.0f), 3 = bf16 (0/0x3F80)
__device__ __forceinline__ bool mask_active(const void* mp, int pix, int flag){
    if (flag == 1) return ((const int*)mp)[pix] != 0;
    if (flag == 0) return ((const uint8_t*)mp)[pix] != 0;
    if (flag == 2) return ((const uint32_t*)mp)[pix] != 0u;
    return ((const uint16_t*)mp)[pix] != 0;
}

// ---------------- P0: probes (mask format, input float format) ---------------------
__global__ __launch_bounds__(256) void probe_k(const void* __restrict__ mask,
                                               const void* __restrict__ fc1w,
                                               uint8_t* __restrict__ ws){
    __shared__ int s_gt1, s_byte, s_f32, s_half, s_bad;
    if (threadIdx.x == 0){ s_gt1=0; s_byte=0; s_f32=0; s_half=0; s_bad=0; }
    __syncthreads();
    const uint32_t* mw = (const uint32_t*)mask;
    int gt1 = 0, bbyte = 0, bf32 = 0, bhalf = 0;
    for (int i = threadIdx.x; i < 16384; i += 256){
        uint32_t w = mw[i];
        if (w > 1u) gt1 = 1;
        uint32_t b0 = w & 0xFFu, b1 = (w>>8)&0xFFu, b2 = (w>>16)&0xFFu, b3 = w>>24;
        if (b0>1u || b1>1u || b2>1u || b3>1u) bbyte = 1;
        if (w != 0u && w != 0x3F800000u) bf32 = 1;
        uint32_t h0 = w & 0xFFFFu, h1 = w >> 16;
        if ((h0 != 0u && h0 != 0x3F80u) || (h1 != 0u && h1 != 0x3F80u)) bhalf = 1;
    }
    if (gt1)   atomicOr(&s_gt1, 1);
    if (bbyte) atomicOr(&s_byte, 1);
    if (bf32)  atomicOr(&s_f32, 1);
    if (bhalf) atomicOr(&s_half, 1);

    const uint32_t* fw = (const uint32_t*)fc1w;
    int bad = 0;
    for (int i = threadIdx.x; i < 4096; i += 256){
        uint32_t w = fw[i];
        uint32_t h0 = w & 0xFFFFu, h1 = w >> 16;
        uint32_t e0 = (h0 >> 7) & 0xFFu, e1 = (h1 >> 7) & 0xFFu;
        if (h0 != 0u && (e0 >= 0xF0u || e0 < 0x5Eu)) bad++;
        if (h1 != 0u && (e1 >= 0xF0u || e1 < 0x5Eu)) bad++;
    }
    if (bad) atomicAdd(&s_bad, bad);
    __syncthreads();
    if (threadIdx.x == 0){
        int flag;
        if      (!s_gt1)  flag = 1;
        else if (!s_byte) flag = 0;
        else if (!s_f32)  flag = 2;
        else if (!s_half) flag = 3;
        else              flag = 0;
        *(int*)(ws + OFF_FLAG) = flag;
        *(int*)(ws + OFF_IFMT) = (s_bad < 400) ? 1 : 0;
    }
}

// ---------------- P1: small weight transposes (w1, w2, fc2) ------------------------
__global__ __launch_bounds__(256) void prep_k(const void* __restrict__ w1,
                                              const void* __restrict__ w2,
                                              const void* __restrict__ fc2w,
                                              uint8_t* __restrict__ ws){
    int t = blockIdx.x * 256 + threadIdx.x;
    int ifmt = *(volatile int*)(ws + OFF_IFMT);
    float* w1t  = (float*)(ws + OFF_W1T);
    float* w2t  = (float*)(ws + OFF_W2T);
    float* fc2t = (float*)(ws + OFF_FC2T);
    if (t < 288){                       // W1T[tap][oc] <- W1[oc][0][tap]
        int tap = t >> 5, oc = t & 31;
        w1t[t] = ldin(w1, oc*9 + tap, ifmt);
    }
    if (t < 18432){                     // W2T[tap][ic][oc] <- W2[oc][ic][tap]
        int oc = t & 63, ic = (t >> 6) & 31, tap = t >> 11;
        w2t[t] = ldin(w2, (oc*32 + ic)*9 + tap, ifmt);
    }
    if (t < 1280){                      // FC2T[k][n] <- fc2w[n][k]
        int k = t / 10, n = t - k*10;
        fc2t[t] = ldin(fc2w, n*128 + k, ifmt);
    }
}

// ---------------- P2: fc1w -> bf16 [128][12544] (k-contiguous, for MFMA A-frag) ----
__global__ __launch_bounds__(256) void fc1wb_k(const void* __restrict__ fc1w,
                                               uint8_t* __restrict__ ws){
    int t = blockIdx.x * 256 + threadIdx.x;   // 6272*256 == 1605632 exactly
    int ifmt = *(volatile int*)(ws + OFF_IFMT);
    ((uint16_t*)(ws + OFF_FC1WB))[t] = (uint16_t)f2bf(ldin(fc1w, t, ifmt));
}

// ---------------- K1a: per-block active count (no atomics) -------------------------
__global__ __launch_bounds__(256) void count_k(const void* __restrict__ mask,
                                               uint8_t* __restrict__ ws){
    int t = blockIdx.x * 256 + threadIdx.x;
    int flag = *(volatile int*)(ws + OFF_FLAG);
    bool act = mask_active(mask, t, flag);
    unsigned long long ball = __ballot(act);
    int lane = threadIdx.x & 63, wid = threadIdx.x >> 6;
    __shared__ int wcnt[4];
    if (lane == 0) wcnt[wid] = __popcll(ball);
    __syncthreads();
    if (threadIdx.x == 0)
        ((int*)(ws + OFF_BLKCNT))[blockIdx.x] = wcnt[0] + wcnt[1] + wcnt[2] + wcnt[3];
}

// ---------------- K1b: exclusive scan of 12544 block counts (1 block) --------------
__global__ __launch_bounds__(256) void scan_k(uint8_t* __restrict__ ws){
    __shared__ int psum[256];
    const int* cnt = (const int*)(ws + OFF_BLKCNT);
    int* off = (int*)(ws + OFF_BLKOFF);
    int t = threadIdx.x;
    int base = t * 49;                       // 256*49 = 12544
    int s = 0;
    for (int i = 0; i < 49; i++) s += cnt[base + i];
    psum[t] = s;
    __syncthreads();
    if (t == 0){
        int run = 0;
        for (int i = 0; i < 256; i++){ int v = psum[i]; psum[i] = run; run += v; }
        *(int*)(ws + OFF_CNT) = run;
    }
    __syncthreads();
    int run = psum[t];
    for (int i = 0; i < 49; i++){ off[base + i] = run; run += cnt[base + i]; }
}

// ---------------- K1c: assign positions (deterministic, no atomics) ----------------
__global__ __launch_bounds__(256) void assign_k(const void* __restrict__ mask,
                                                uint8_t* __restrict__ ws){
    int t = blockIdx.x * 256 + threadIdx.x;            // pixel id = b*784 + yx
    int flag = *(volatile int*)(ws + OFF_FLAG);
    int b = t / HW; int yx = t - b*HW;
    bool act = mask_active(mask, t, flag);

    unsigned long long ball = __ballot(act);
    int lane = threadIdx.x & 63;
    int wid  = threadIdx.x >> 6;
    __shared__ int wbase[4];
    if (lane == 0) wbase[wid] = __popcll(ball);
    __syncthreads();
    if (threadIdx.x == 0){
        int base = ((const int*)(ws + OFF_BLKOFF))[blockIdx.x];
        int s0 = wbase[0], s1 = wbase[1], s2 = wbase[2];
        wbase[0] = base;
        wbase[1] = base + s0;
        wbase[2] = base + s0 + s1;
        wbase[3] = base + s0 + s1 + s2;
    }
    __syncthreads();

    int idx = -1;
    if (act){
        int pos = wbase[wid] + __popcll(ball & ((1ull << lane) - 1ull));
        if (pos < LMAX){
            ((uint32_t*)(ws + OFF_LIST))[pos] = ((uint32_t)yx << 12) | (uint32_t)b;
            idx = pos;
        }
    }
    ((int*)(ws + OFF_IDX))[t] = idx;    // [b][yx], coalesced
}

// ---------------- K2: conv1 (1->32) + relu at active sites -> H1C bf16 -------------
__global__ __launch_bounds__(256) void conv1_k(const void* __restrict__ x,
                                               uint8_t* __restrict__ ws){
    int e = blockIdx.x * 256 + threadIdx.x;
    int count = *(volatile int*)(ws + OFF_CNT);
    if (count > LMAX) count = LMAX;
    if (e >= count) return;
    int ifmt = *(volatile int*)(ws + OFF_IFMT);
    const float* w1t = (const float*)(ws + OFF_W1T);
    uint32_t code = ((const uint32_t*)(ws + OFF_LIST))[e];
    int b = code & 4095; int yx = code >> 12;
    int y = yx / IMW; int xx = yx - y*IMW;

    float acc[32];
    #pragma unroll
    for (int i = 0; i < 32; i++) acc[i] = 0.f;
    #pragma unroll
    for (int ky = 0; ky < 3; ky++){
        #pragma unroll
        for (int kx = 0; kx < 3; kx++){
            int ny = y + ky - 1, nx = xx + kx - 1;
            bool inb = ((unsigned)ny < 28u) && ((unsigned)nx < 28u);
            float xv = inb ? ldin(x, (size_t)b*HW + ny*IMW + nx, ifmt) : 0.f;
            const float* wt = w1t + (ky*3 + kx)*32;
            #pragma unroll
            for (int oc = 0; oc < 32; oc++) acc[oc] = fmaf(xv, wt[oc], acc[oc]);
        }
    }
    uint32_t o[16];
    #pragma unroll
    for (int i = 0; i < 16; i++)
        o[i] = packbf(fmaxf(acc[2*i], 0.f), fmaxf(acc[2*i+1], 0.f));
    uint4* dst = (uint4*)(ws + OFF_H1C + (size_t)e*64);
    dst[0] = make_uint4(o[0],o[1],o[2],o[3]);
    dst[1] = make_uint4(o[4],o[5],o[6],o[7]);
    dst[2] = make_uint4(o[8],o[9],o[10],o[11]);
    dst[3] = make_uint4(o[12],o[13],o[14],o[15]);
}

// ---------------- K3: conv2 (32->64) at active sites, fused oc, coalesced imap -----
__global__ __launch_bounds__(256) void conv2_k(uint8_t* __restrict__ ws){
    int e = blockIdx.x * 256 + threadIdx.x;
    int count = *(volatile int*)(ws + OFF_CNT);
    if (count > LMAX) count = LMAX;
    if (e >= count) return;
    const float*    w2t  = (const float*)(ws + OFF_W2T);
    const uint32_t* h1c  = (const uint32_t*)(ws + OFF_H1C);
    const int*      imap = (const int*)(ws + OFF_IDX);   // [b][yx]
    uint32_t code = ((const uint32_t*)(ws + OFF_LIST))[e];
    int b = code & 4095; int yx = code >> 12;
    int y = yx / IMW; int xx = yx - y*IMW;
    const int* imb = imap + (size_t)b*HW;

    int nidx[9];
    #pragma unroll
    for (int tap = 0; tap < 9; tap++){
        int dy = tap/3 - 1, dx = tap - (tap/3)*3 - 1;
        int ny = y + dy, nx = xx + dx;
        bool inb = ((unsigned)ny < 28u) && ((unsigned)nx < 28u);
        nidx[tap] = inb ? imb[ny*IMW + nx] : -1;
    }

    float acc[64];
    #pragma unroll
    for (int i = 0; i < 64; i++) acc[i] = 0.f;
    for (int tap = 0; tap < 9; tap++){
        int ni = nidx[tap];
        uint32_t hv[16];
        if (ni >= 0){
            const uint4* q = (const uint4*)(h1c + (size_t)ni*16);
            uint4 a = q[0], c = q[1], d = q[2], f = q[3];
            hv[0]=a.x; hv[1]=a.y; hv[2]=a.z; hv[3]=a.w;
            hv[4]=c.x; hv[5]=c.y; hv[6]=c.z; hv[7]=c.w;
            hv[8]=d.x; hv[9]=d.y; hv[10]=d.z; hv[11]=d.w;
            hv[12]=f.x; hv[13]=f.y; hv[14]=f.z; hv[15]=f.w;
        } else {
            #pragma unroll
            for (int i = 0; i < 16; i++) hv[i] = 0u;
        }
        const float* wt = w2t + tap*2048;
        #pragma unroll 4
        for (int icp = 0; icp < 16; icp++){
            float v0 = bflo(hv[icp]), v1 = bfhi(hv[icp]);
            const float* wa = wt + (2*icp)*64;
            const float* wb = wa + 64;
            #pragma unroll
            for (int oc = 0; oc < 64; oc++){
                acc[oc] = fmaf(v0, wa[oc], acc[oc]);
                acc[oc] = fmaf(v1, wb[oc], acc[oc]);
            }
        }
    }
    uint32_t o[32];
    #pragma unroll
    for (int i = 0; i < 32; i++)
        o[i] = packbf(fmaxf(acc[2*i], 0.f), fmaxf(acc[2*i+1], 0.f));
    uint4* dst = (uint4*)(ws + OFF_COMPACT + (size_t)e*128);
    #pragma unroll
    for (int q = 0; q < 8; q++)
        dst[q] = make_uint4(o[4*q], o[4*q+1], o[4*q+2], o[4*q+3]);
}

// ---------------- K4: maxpool 2x2 -> pooled[b][k=oc*196+cell] bf16 -----------------
__global__ __launch_bounds__(256) void pool_k(uint8_t* __restrict__ ws){
    int b = blockIdx.x;
    int cell = threadIdx.x;
    if (cell >= NCELL) return;
    int py = cell / 14, px = cell - py*14;
    const int* imb = (const int*)(ws + OFF_IDX) + (size_t)b*HW;   // [b][yx]
    float mx[64];
    #pragma unroll
    for (int i = 0; i < 64; i++) mx[i] = 0.f;
    #pragma unroll
    for (int s = 0; s < 4; s++){
        int yy = 2*py + (s >> 1), xxp = 2*px + (s & 1);
        int idx = imb[yy*IMW + xxp];
        if (idx >= 0){
            const uint4* row = (const uint4*)(ws + OFF_COMPACT + (size_t)idx*128);
            #pragma unroll
            for (int q = 0; q < 8; q++){
                uint4 v = row[q];
                mx[q*8+0] = fmaxf(mx[q*8+0], bflo(v.x)); mx[q*8+1] = fmaxf(mx[q*8+1], bfhi(v.x));
                mx[q*8+2] = fmaxf(mx[q*8+2], bflo(v.y)); mx[q*8+3] = fmaxf(mx[q*8+3], bfhi(v.y));
                mx[q*8+4] = fmaxf(mx[q*8+4], bflo(v.z)); mx[q*8+5] = fmaxf(mx[q*8+5], bfhi(v.z));
                mx[q*8+6] = fmaxf(mx[q*8+6], bflo(v.w)); mx[q*8+7] = fmaxf(mx[q*8+7], bfhi(v.w));
            }
        }
    }
    uint16_t* prow = (uint16_t*)(ws + OFF_POOLED) + (size_t)b*K_FC;
    #pragma unroll
    for (int oc = 0; oc < 64; oc++)
        prow[oc*NCELL + cell] = (uint16_t)f2bf(mx[oc]);
}

// ---------------- K5: fc1 MFMA GEMM: h3[n][b] = fc1wb[n][:] . pooled[b][:] ---------
__global__ __launch_bounds__(256) void fc1mfma_k(uint8_t* __restrict__ ws){
    int wid = threadIdx.x >> 6, lane = threadIdx.x & 63;
    int bidx = blockIdx.x;
    int kz = bidx >> 7;               // 0..3
    int rem = bidx & 127;
    int nt = rem >> 6;                // 0..1
    int bt = rem & 63;                // 0..63
    int n0 = nt*64 + (wid >> 1)*32;
    int b0 = bt*64 + (wid & 1)*32;
    int l15 = lane & 15;
    int kb  = (lane >> 4) * 8;

    const uint16_t* W = (const uint16_t*)(ws + OFF_FC1WB);
    const uint16_t* P = (const uint16_t*)(ws + OFF_POOLED);
    const uint16_t* wa0 = W + (size_t)(n0 + l15)*K_FC + kb;
    const uint16_t* wa1 = wa0 + (size_t)16*K_FC;
    const uint16_t* pb0 = P + (size_t)(b0 + l15)*K_FC + kb;
    const uint16_t* pb1 = pb0 + (size_t)16*K_FC;

    f32x4 acc00 = {0.f,0.f,0.f,0.f}, acc01 = acc00, acc10 = acc00, acc11 = acc00;
    int k0 = kz * 3136;
    for (int k = k0; k < k0 + 3136; k += 64){
        bf16x8 a0 = *(const bf16x8*)(wa0 + k);
        bf16x8 a1 = *(const bf16x8*)(wa1 + k);
        bf16x8 p0 = *(const bf16x8*)(pb0 + k);
        bf16x8 p1 = *(const bf16x8*)(pb1 + k);
        bf16x8 a0b = *(const bf16x8*)(wa0 + k + 32);
        bf16x8 a1b = *(const bf16x8*)(wa1 + k + 32);
        bf16x8 p0b = *(const bf16x8*)(pb0 + k + 32);
        bf16x8 p1b = *(const bf16x8*)(pb1 + k + 32);
        acc00 = __builtin_amdgcn_mfma_f32_16x16x32_bf16(a0, p0, acc00, 0, 0, 0);
        acc01 = __builtin_amdgcn_mfma_f32_16x16x32_bf16(a0, p1, acc01, 0, 0, 0);
        acc10 = __builtin_amdgcn_mfma_f32_16x16x32_bf16(a1, p0, acc10, 0, 0, 0);
        acc11 = __builtin_amdgcn_mfma_f32_16x16x32_bf16(a1, p1, acc11, 0, 0, 0);
        acc00 = __builtin_amdgcn_mfma_f32_16x16x32_bf16(a0b, p0b, acc00, 0, 0, 0);
        acc01 = __builtin_amdgcn_mfma_f32_16x16x32_bf16(a0b, p1b, acc01, 0, 0, 0);
        acc10 = __builtin_amdgcn_mfma_f32_16x16x32_bf16(a1b, p0b, acc10, 0, 0, 0);
        acc11 = __builtin_amdgcn_mfma_f32_16x16x32_bf16(a1b, p1b, acc11, 0, 0, 0);
    }

    // D layout: col = lane&15 (b-local), row = (lane>>4)*4 + r (n-local)
    float* partial = (float*)(ws + OFF_PARTIAL);
    int rl = (lane >> 4) * 4;
    #pragma unroll
    for (int r = 0; r < 4; r++){
        size_t rowA = (size_t)(kz*128 + n0 + rl + r)*BATCH;
        size_t rowB = (size_t)(kz*128 + n0 + 16 + rl + r)*BATCH;
        partial[rowA + b0 + l15]      = acc00[r];
        partial[rowA + b0 + 16 + l15] = acc01[r];
        partial[rowB + b0 + l15]      = acc10[r];
        partial[rowB + b0 + 16 + l15] = acc11[r];
    }
}

// ---------------- K5b: reduce 4 partials + bias + relu -> h3[n][b] f32 -------------
__global__ __launch_bounds__(256) void fc1red_k(const void* __restrict__ fc1b,
                                                uint8_t* __restrict__ ws){
    int t = blockIdx.x * 256 + threadIdx.x;  // t = n*4096 + b
    int b = t & 4095; int n = t >> 12;
    int ifmt = *(volatile int*)(ws + OFF_IFMT);
    const float* partial = (const float*)(ws + OFF_PARTIAL);
    float s = ldin(fc1b, n, ifmt);
    #pragma unroll
    for (int kc = 0; kc < 4; kc++) s += partial[(size_t)(kc*128 + n)*BATCH + b];
    ((float*)(ws + OFF_H3))[t] = fmaxf(s, 0.f);
}

// ---------------- K6: fc2 + log_softmax -> out [B][10] f32 -------------------------
__global__ __launch_bounds__(256) void fc2_k(const void* __restrict__ fc2b,
                                             uint8_t* __restrict__ ws,
                                             float* __restrict__ out){
    int b = blockIdx.x * 256 + threadIdx.x;  // 4096 threads
    int ifmt = *(volatile int*)(ws + OFF_IFMT);
    const float* h3   = (const float*)(ws + OFF_H3);
    const float* fc2t = (const float*)(ws + OFF_FC2T);
    float acc[10];
    #pragma unroll
    for (int n = 0; n < 10; n++) acc[n] = ldin(fc2b, n, ifmt);
    for (int k = 0; k < 128; k++){
        float v = h3[(size_t)k*BATCH + b];
        const float* wk = fc2t + k*10;
        #pragma unroll
        for (int n = 0; n < 10; n++) acc[n] = fmaf(v, wk[n], acc[n]);
    }
    float m = acc[0];
    #pragma unroll
    for (int n = 1; n < 10; n++) m = fmaxf(m, acc[n]);
    float s = 0.f;
    #pragma unroll
    for (int n = 0; n < 10; n++) s += expf(acc[n] - m);
    float ls = logf(s);
    #pragma unroll
    for (int n = 0; n < 10; n++) out[(size_t)b*10 + n] = acc[n] - m - ls;
}

extern "C" void kernel_launch(void* const* d_in, const int* in_sizes, int n_in,
                              void* d_out, int out_size, void* d_ws, size_t ws_size,
                              hipStream_t stream){
    const void* x    = d_in[0];
    const void* mask = d_in[1];
    const void* w1   = d_in[2];
    const void* w2   = d_in[3];
    const void* fc1w = d_in[4];
    const void* fc1b = d_in[5];
    const void* fc2w = d_in[6];
    const void* fc2b = d_in[7];
    uint8_t* ws = (uint8_t*)d_ws;
    float* out = (float*)d_out;

    hipLaunchKernelGGL(probe_k,    dim3(1),     dim3(256), 0, stream, mask, fc1w, ws);
    hipLaunchKernelGGL(prep_k,     dim3(72),    dim3(256), 0, stream, w1, w2, fc2w, ws);
    hipLaunchKernelGGL(fc1wb_k,    dim3(6272),  dim3(256), 0, stream, fc1w, ws);
    hipLaunchKernelGGL(count_k,    dim3(NBLK),  dim3(256), 0, stream, mask, ws);
    hipLaunchKernelGGL(scan_k,     dim3(1),     dim3(256), 0, stream, ws);
    hipLaunchKernelGGL(assign_k,   dim3(NBLK),  dim3(256), 0, stream, mask, ws);
    hipLaunchKernelGGL(conv1_k,    dim3(2560),  dim3(256), 0, stream, x, ws);
    hipLaunchKernelGGL(conv2_k,    dim3(2560),  dim3(256), 0, stream, ws);
    hipLaunchKernelGGL(pool_k,     dim3(4096),  dim3(256), 0, stream, ws);
    hipLaunchKernelGGL(fc1mfma_k,  dim3(512),   dim3(256), 0, stream, ws);
    hipLaunchKernelGGL(fc1red_k,   dim3(2048),  dim3(256), 0, stream, fc1b, ws);
    hipLaunchKernelGGL(fc2_k,      dim3(16),    dim3(256), 0, stream, fc2b, ws, out);
}

// Round 10
// 473.234 us; speedup vs baseline: 6.5424x; 1.4122x over previous
//
#include <hip/hip_runtime.h>
#include <hip/hip_bf16.h>
#include <stdint.h>

// Problem constants
#define BATCH 4096
#define HW 784          // 28*28
#define IMW 28
#define NCELL 196       // 14*14
#define K_FC 12544
#define LMAX 655360     // active-site list capacity (expected ~642,253 = mean+18sigma)
#define NBLK 12544      // compaction grid blocks (NPIX/256)

// Workspace layout (bytes). Peak 204 MiB (known to fit).
#define OFF_FLAG    0ull               // mask storage format
#define OFF_CNT     4ull               // active-site counter
#define OFF_IFMT    8ull               // input float format: 0=f32, 1=bf16
#define OFF_W1T     1024ull            // f32[9][32]        1152 B
#define OFF_W2B     4096ull            // bf16[9][64][32]   36864 B (ends 40960)
#define OFF_FC2T    81920ull           // f32[128][10]      5120 B
#define OFF_H3      (512ull<<10)       // f32[128][4096]    2 MiB (ends 2.5M)
#define OFF_FC1WB   (3ull<<20)         // bf16[128][12544]  3.06 MiB (ends 6.2M)
#define OFF_BLKCNT  (7ull<<20)         // i32[NBLK]         49 KiB
#define OFF_BLKOFF  (8ull<<20)         // i32[NBLK]         49 KiB
#define OFF_IDX     (10ull<<20)        // i32[4096][784]  (b-major) 12.25 MiB (ends 22.25M)
#define OFF_LIST    (23ull<<20)        // u32[LMAX]         2.5 MiB (ends 25.5M)
#define OFF_COMPACT (26ull<<20)        // bf16[LMAX][64]    80 MiB (ends 106M)
#define OFF_PARTIAL (26ull<<20)        // f32[4][128][4096] 8 MiB — aliases COMPACT (dead by then)
#define OFF_H1C     (106ull<<20)       // bf16[LMAX][32]    40 MiB (ends 146M)
#define OFF_POOLED  (106ull<<20)       // bf16[4096][12544] (b-major) 98 MiB — aliases H1C (dead), ends 204M

typedef short bf16x8 __attribute__((ext_vector_type(8)));   // 8 bf16 (4 VGPRs)
typedef float f32x4  __attribute__((ext_vector_type(4)));

__device__ __forceinline__ float bflo(uint32_t u){ return __uint_as_float(u << 16); }
__device__ __forceinline__ float bfhi(uint32_t u){ return __uint_as_float(u & 0xFFFF0000u); }
__device__ __forceinline__ float bfu16(uint16_t h){ return __uint_as_float(((uint32_t)h) << 16); }
__device__ __forceinline__ uint32_t f2bf(float f){
    uint32_t u = __float_as_uint(f);
    return (u + 0x7FFFu + ((u >> 16) & 1u)) >> 16;   // RNE
}
__device__ __forceinline__ uint32_t packbf(float a, float b){
    return f2bf(a) | (f2bf(b) << 16);
}

// Input float tensor load honoring probed storage format (0=f32, 1=bf16)
__device__ __forceinline__ float ldin(const void* p, size_t i, int ifmt){
    return ifmt ? bfu16(((const uint16_t*)p)[i]) : ((const float*)p)[i];
}

// mask storage: 0 = u8 bytes, 1 = int32, 2 = f32 (0/1.0f), 3 = bf16 (0/0x3F80)
__device__ __forceinline__ bool mask_active(const void* mp, int pix, int flag){
    if (flag == 1) return ((const int*)mp)[pix] != 0;
    if (flag == 0) return ((const uint8_t*)mp)[pix] != 0;
    if (flag == 2) return ((const uint32_t*)mp)[pix] != 0u;
    return ((const uint16_t*)mp)[pix] != 0;
}

// ---------------- P0: probes (mask format, input float format) ---------------------
__global__ __launch_bounds__(256) void probe_k(const void* __restrict__ mask,
                                               const void* __restrict__ fc1w,
                                               uint8_t* __restrict__ ws){
    __shared__ int s_gt1, s_byte, s_f32, s_half, s_bad;
    if (threadIdx.x == 0){ s_gt1=0; s_byte=0; s_f32=0; s_half=0; s_bad=0; }
    __syncthreads();
    const uint32_t* mw = (const uint32_t*)mask;
    int gt1 = 0, bbyte = 0, bf32 = 0, bhalf = 0;
    for (int i = threadIdx.x; i < 16384; i += 256){
        uint32_t w = mw[i];
        if (w > 1u) gt1 = 1;
        uint32_t b0 = w & 0xFFu, b1 = (w>>8)&0xFFu, b2 = (w>>16)&0xFFu, b3 = w>>24;
        if (b0>1u || b1>1u || b2>1u || b3>1u) bbyte = 1;
        if (w != 0u && w != 0x3F800000u) bf32 = 1;
        uint32_t h0 = w & 0xFFFFu, h1 = w >> 16;
        if ((h0 != 0u && h0 != 0x3F80u) || (h1 != 0u && h1 != 0x3F80u)) bhalf = 1;
    }
    if (gt1)   atomicOr(&s_gt1, 1);
    if (bbyte) atomicOr(&s_byte, 1);
    if (bf32)  atomicOr(&s_f32, 1);
    if (bhalf) atomicOr(&s_half, 1);

    const uint32_t* fw = (const uint32_t*)fc1w;
    int bad = 0;
    for (int i = threadIdx.x; i < 4096; i += 256){
        uint32_t w = fw[i];
        uint32_t h0 = w & 0xFFFFu, h1 = w >> 16;
        uint32_t e0 = (h0 >> 7) & 0xFFu, e1 = (h1 >> 7) & 0xFFu;
        if (h0 != 0u && (e0 >= 0xF0u || e0 < 0x5Eu)) bad++;
        if (h1 != 0u && (e1 >= 0xF0u || e1 < 0x5Eu)) bad++;
    }
    if (bad) atomicAdd(&s_bad, bad);
    __syncthreads();
    if (threadIdx.x == 0){
        int flag;
        if      (!s_gt1)  flag = 1;
        else if (!s_byte) flag = 0;
        else if (!s_f32)  flag = 2;
        else if (!s_half) flag = 3;
        else              flag = 0;
        *(int*)(ws + OFF_FLAG) = flag;
        *(int*)(ws + OFF_IFMT) = (s_bad < 400) ? 1 : 0;
    }
}

// ---------------- P1: small weight preps (w1 f32, w2 bf16 frag layout, fc2 f32) ----
__global__ __launch_bounds__(256) void prep_k(const void* __restrict__ w1,
                                              const void* __restrict__ w2,
                                              const void* __restrict__ fc2w,
                                              uint8_t* __restrict__ ws){
    int t = blockIdx.x * 256 + threadIdx.x;
    int ifmt = *(volatile int*)(ws + OFF_IFMT);
    float*    w1t  = (float*)(ws + OFF_W1T);
    uint16_t* w2b  = (uint16_t*)(ws + OFF_W2B);
    float*    fc2t = (float*)(ws + OFF_FC2T);
    if (t < 288){                       // W1T[tap][oc] <- W1[oc][0][tap]
        int tap = t >> 5, oc = t & 31;
        w1t[t] = ldin(w1, oc*9 + tap, ifmt);
    }
    if (t < 18432){                     // W2B[tap][oc][ic] <- W2[oc][ic][tap]  (bf16, A-frag rows)
        int ic = t & 31, oc = (t >> 5) & 63, tap = t >> 11;
        w2b[t] = (uint16_t)f2bf(ldin(w2, (oc*32 + ic)*9 + tap, ifmt));
    }
    if (t < 1280){                      // FC2T[k][n] <- fc2w[n][k]
        int k = t / 10, n = t - k*10;
        fc2t[t] = ldin(fc2w, n*128 + k, ifmt);
    }
}

// ---------------- P2: fc1w -> bf16 [128][12544] (k-contiguous, for MFMA A-frag) ----
__global__ __launch_bounds__(256) void fc1wb_k(const void* __restrict__ fc1w,
                                               uint8_t* __restrict__ ws){
    int t = blockIdx.x * 256 + threadIdx.x;   // 6272*256 == 1605632 exactly
    int ifmt = *(volatile int*)(ws + OFF_IFMT);
    ((uint16_t*)(ws + OFF_FC1WB))[t] = (uint16_t)f2bf(ldin(fc1w, t, ifmt));
}

// ---------------- K1a: per-block active count (no atomics) -------------------------
__global__ __launch_bounds__(256) void count_k(const void* __restrict__ mask,
                                               uint8_t* __restrict__ ws){
    int t = blockIdx.x * 256 + threadIdx.x;
    int flag = *(volatile int*)(ws + OFF_FLAG);
    bool act = mask_active(mask, t, flag);
    unsigned long long ball = __ballot(act);
    int lane = threadIdx.x & 63, wid = threadIdx.x >> 6;
    __shared__ int wcnt[4];
    if (lane == 0) wcnt[wid] = __popcll(ball);
    __syncthreads();
    if (threadIdx.x == 0)
        ((int*)(ws + OFF_BLKCNT))[blockIdx.x] = wcnt[0] + wcnt[1] + wcnt[2] + wcnt[3];
}

// ---------------- K1b: exclusive scan of 12544 block counts (1 block) --------------
__global__ __launch_bounds__(256) void scan_k(uint8_t* __restrict__ ws){
    __shared__ int psum[256];
    const int* cnt = (const int*)(ws + OFF_BLKCNT);
    int* off = (int*)(ws + OFF_BLKOFF);
    int t = threadIdx.x;
    int base = t * 49;                       // 256*49 = 12544
    int s = 0;
    for (int i = 0; i < 49; i++) s += cnt[base + i];
    psum[t] = s;
    __syncthreads();
    if (t == 0){
        int run = 0;
        for (int i = 0; i < 256; i++){ int v = psum[i]; psum[i] = run; run += v; }
        *(int*)(ws + OFF_CNT) = run;
    }
    __syncthreads();
    int run = psum[t];
    for (int i = 0; i < 49; i++){ off[base + i] = run; run += cnt[base + i]; }
}

// ---------------- K1c: assign positions (deterministic, no atomics) ----------------
__global__ __launch_bounds__(256) void assign_k(const void* __restrict__ mask,
                                                uint8_t* __restrict__ ws){
    int t = blockIdx.x * 256 + threadIdx.x;            // pixel id = b*784 + yx
    int flag = *(volatile int*)(ws + OFF_FLAG);
    int b = t / HW; int yx = t - b*HW;
    bool act = mask_active(mask, t, flag);

    unsigned long long ball = __ballot(act);
    int lane = threadIdx.x & 63;
    int wid  = threadIdx.x >> 6;
    __shared__ int wbase[4];
    if (lane == 0) wbase[wid] = __popcll(ball);
    __syncthreads();
    if (threadIdx.x == 0){
        int base = ((const int*)(ws + OFF_BLKOFF))[blockIdx.x];
        int s0 = wbase[0], s1 = wbase[1], s2 = wbase[2];
        wbase[0] = base;
        wbase[1] = base + s0;
        wbase[2] = base + s0 + s1;
        wbase[3] = base + s0 + s1 + s2;
    }
    __syncthreads();

    int idx = -1;
    if (act){
        int pos = wbase[wid] + __popcll(ball & ((1ull << lane) - 1ull));
        if (pos < LMAX){
            ((uint32_t*)(ws + OFF_LIST))[pos] = ((uint32_t)yx << 12) | (uint32_t)b;
            idx = pos;
        }
    }
    ((int*)(ws + OFF_IDX))[t] = idx;    // [b][yx], coalesced
}

// ---------------- K2: conv1 (1->32) + relu at active sites -> H1C bf16 -------------
__global__ __launch_bounds__(256) void conv1_k(const void* __restrict__ x,
                                               uint8_t* __restrict__ ws){
    int e = blockIdx.x * 256 + threadIdx.x;
    int count = *(volatile int*)(ws + OFF_CNT);
    if (count > LMAX) count = LMAX;
    if (e >= count) return;
    int ifmt = *(volatile int*)(ws + OFF_IFMT);
    const float* w1t = (const float*)(ws + OFF_W1T);
    uint32_t code = ((const uint32_t*)(ws + OFF_LIST))[e];
    int b = code & 4095; int yx = code >> 12;
    int y = yx / IMW; int xx = yx - y*IMW;

    float acc[32];
    #pragma unroll
    for (int i = 0; i < 32; i++) acc[i] = 0.f;
    #pragma unroll
    for (int ky = 0; ky < 3; ky++){
        #pragma unroll
        for (int kx = 0; kx < 3; kx++){
            int ny = y + ky - 1, nx = xx + kx - 1;
            bool inb = ((unsigned)ny < 28u) && ((unsigned)nx < 28u);
            float xv = inb ? ldin(x, (size_t)b*HW + ny*IMW + nx, ifmt) : 0.f;
            const float* wt = w1t + (ky*3 + kx)*32;
            #pragma unroll
            for (int oc = 0; oc < 32; oc++) acc[oc] = fmaf(xv, wt[oc], acc[oc]);
        }
    }
    uint32_t o[16];
    #pragma unroll
    for (int i = 0; i < 16; i++)
        o[i] = packbf(fmaxf(acc[2*i], 0.f), fmaxf(acc[2*i+1], 0.f));
    uint4* dst = (uint4*)(ws + OFF_H1C + (size_t)e*64);
    dst[0] = make_uint4(o[0],o[1],o[2],o[3]);
    dst[1] = make_uint4(o[4],o[5],o[6],o[7]);
    dst[2] = make_uint4(o[8],o[9],o[10],o[11]);
    dst[3] = make_uint4(o[12],o[13],o[14],o[15]);
}

// ---------------- K3: conv2 via MFMA: 16 sites/wave, 9 taps x 4 ocq ----------------
// A = W2B[tap][oc][ic] (row=oc, k=ic), B = gathered H1C rows (col=site, k=ic).
// D: col=lane&15 (site), row=(lane>>4)*4+r (oc-local). Same verified layout as fc1.
__global__ __launch_bounds__(256) void conv2mfma_k(uint8_t* __restrict__ ws){
    int count = *(volatile int*)(ws + OFF_CNT);
    if (count > LMAX) count = LMAX;
    int gw   = (blockIdx.x * 256 + threadIdx.x) >> 6;
    int nw   = (gridDim.x * 256) >> 6;
    int lane = threadIdx.x & 63;
    int l15  = lane & 15;
    int kb   = (lane >> 4) * 8;          // ic sub-block for this lane group

    const uint16_t* w2b  = (const uint16_t*)(ws + OFF_W2B);
    const uint16_t* h1c  = (const uint16_t*)(ws + OFF_H1C);
    const int*      imap = (const int*)(ws + OFF_IDX);   // [b][yx]
    const uint32_t* list = (const uint32_t*)(ws + OFF_LIST);

    int ntiles = (count + 15) >> 4;
    for (int tile = gw; tile < ntiles; tile += nw){
        int s = tile*16 + l15;
        bool sv = s < count;
        uint32_t code = sv ? list[s] : 0;
        int b = code & 4095; int yx = code >> 12;
        int y = yx / IMW; int xx = yx - y*IMW;
        const int* imb = imap + (size_t)b*HW;

        f32x4 acc0 = {0.f,0.f,0.f,0.f}, acc1 = acc0, acc2 = acc0, acc3 = acc0;
        #pragma unroll
        for (int tap = 0; tap < 9; tap++){
            int dy = tap/3 - 1, dx = tap - (tap/3)*3 - 1;
            int ny = y + dy, nx = xx + dx;
            bool inb = sv && ((unsigned)ny < 28u) && ((unsigned)nx < 28u);
            int ni = inb ? imb[ny*IMW + nx] : -1;
            bf16x8 bfrag = {0,0,0,0,0,0,0,0};
            if (ni >= 0)
                bfrag = *(const bf16x8*)(h1c + (size_t)ni*32 + kb);
            const uint16_t* wt = w2b + tap*2048;   // [64oc][32ic]
            bf16x8 a0 = *(const bf16x8*)(wt + (l15     )*32 + kb);
            bf16x8 a1 = *(const bf16x8*)(wt + (l15 + 16)*32 + kb);
            bf16x8 a2 = *(const bf16x8*)(wt + (l15 + 32)*32 + kb);
            bf16x8 a3 = *(const bf16x8*)(wt + (l15 + 48)*32 + kb);
            acc0 = __builtin_amdgcn_mfma_f32_16x16x32_bf16(a0, bfrag, acc0, 0, 0, 0);
            acc1 = __builtin_amdgcn_mfma_f32_16x16x32_bf16(a1, bfrag, acc1, 0, 0, 0);
            acc2 = __builtin_amdgcn_mfma_f32_16x16x32_bf16(a2, bfrag, acc2, 0, 0, 0);
            acc3 = __builtin_amdgcn_mfma_f32_16x16x32_bf16(a3, bfrag, acc3, 0, 0, 0);
        }
        if (sv){
            int rl = (lane >> 4) * 4;
            uint8_t* crow = ws + OFF_COMPACT + (size_t)s*128;
            uint2 v;
            v.x = packbf(fmaxf(acc0[0],0.f), fmaxf(acc0[1],0.f));
            v.y = packbf(fmaxf(acc0[2],0.f), fmaxf(acc0[3],0.f));
            *(uint2*)(crow + (0*16 + rl)*2) = v;
            v.x = packbf(fmaxf(acc1[0],0.f), fmaxf(acc1[1],0.f));
            v.y = packbf(fmaxf(acc1[2],0.f), fmaxf(acc1[3],0.f));
            *(uint2*)(crow + (1*16 + rl)*2) = v;
            v.x = packbf(fmaxf(acc2[0],0.f), fmaxf(acc2[1],0.f));
            v.y = packbf(fmaxf(acc2[2],0.f), fmaxf(acc2[3],0.f));
            *(uint2*)(crow + (2*16 + rl)*2) = v;
            v.x = packbf(fmaxf(acc3[0],0.f), fmaxf(acc3[1],0.f));
            v.y = packbf(fmaxf(acc3[2],0.f), fmaxf(acc3[3],0.f));
            *(uint2*)(crow + (3*16 + rl)*2) = v;
        }
    }
}

// ---------------- K4: maxpool 2x2 -> pooled[b][k=oc*196+cell] bf16 -----------------
__global__ __launch_bounds__(256) void pool_k(uint8_t* __restrict__ ws){
    int b = blockIdx.x;
    int cell = threadIdx.x;
    if (cell >= NCELL) return;
    int py = cell / 14, px = cell - py*14;
    const int* imb = (const int*)(ws + OFF_IDX) + (size_t)b*HW;   // [b][yx]
    float mx[64];
    #pragma unroll
    for (int i = 0; i < 64; i++) mx[i] = 0.f;
    #pragma unroll
    for (int s = 0; s < 4; s++){
        int yy = 2*py + (s >> 1), xxp = 2*px + (s & 1);
        int idx = imb[yy*IMW + xxp];
        if (idx >= 0){
            const uint4* row = (const uint4*)(ws + OFF_COMPACT + (size_t)idx*128);
            #pragma unroll
            for (int q = 0; q < 8; q++){
                uint4 v = row[q];
                mx[q*8+0] = fmaxf(mx[q*8+0], bflo(v.x)); mx[q*8+1] = fmaxf(mx[q*8+1], bfhi(v.x));
                mx[q*8+2] = fmaxf(mx[q*8+2], bflo(v.y)); mx[q*8+3] = fmaxf(mx[q*8+3], bfhi(v.y));
                mx[q*8+4] = fmaxf(mx[q*8+4], bflo(v.z)); mx[q*8+5] = fmaxf(mx[q*8+5], bfhi(v.z));
                mx[q*8+6] = fmaxf(mx[q*8+6], bflo(v.w)); mx[q*8+7] = fmaxf(mx[q*8+7], bfhi(v.w));
            }
        }
    }
    uint16_t* prow = (uint16_t*)(ws + OFF_POOLED) + (size_t)b*K_FC;
    #pragma unroll
    for (int oc = 0; oc < 64; oc++)
        prow[oc*NCELL + cell] = (uint16_t)f2bf(mx[oc]);
}

// ---------------- K5: fc1 MFMA GEMM: h3[n][b] = fc1wb[n][:] . pooled[b][:] ---------
__global__ __launch_bounds__(256) void fc1mfma_k(uint8_t* __restrict__ ws){
    int wid = threadIdx.x >> 6, lane = threadIdx.x & 63;
    int bidx = blockIdx.x;
    int kz = bidx >> 7;               // 0..3
    int rem = bidx & 127;
    int nt = rem >> 6;                // 0..1
    int bt = rem & 63;                // 0..63
    int n0 = nt*64 + (wid >> 1)*32;
    int b0 = bt*64 + (wid & 1)*32;
    int l15 = lane & 15;
    int kb  = (lane >> 4) * 8;

    const uint16_t* W = (const uint16_t*)(ws + OFF_FC1WB);
    const uint16_t* P = (const uint16_t*)(ws + OFF_POOLED);
    const uint16_t* wa0 = W + (size_t)(n0 + l15)*K_FC + kb;
    const uint16_t* wa1 = wa0 + (size_t)16*K_FC;
    const uint16_t* pb0 = P + (size_t)(b0 + l15)*K_FC + kb;
    const uint16_t* pb1 = pb0 + (size_t)16*K_FC;

    f32x4 acc00 = {0.f,0.f,0.f,0.f}, acc01 = acc00, acc10 = acc00, acc11 = acc00;
    int k0 = kz * 3136;
    for (int k = k0; k < k0 + 3136; k += 64){
        bf16x8 a0 = *(const bf16x8*)(wa0 + k);
        bf16x8 a1 = *(const bf16x8*)(wa1 + k);
        bf16x8 p0 = *(const bf16x8*)(pb0 + k);
        bf16x8 p1 = *(const bf16x8*)(pb1 + k);
        bf16x8 a0b = *(const bf16x8*)(wa0 + k + 32);
        bf16x8 a1b = *(const bf16x8*)(wa1 + k + 32);
        bf16x8 p0b = *(const bf16x8*)(pb0 + k + 32);
        bf16x8 p1b = *(const bf16x8*)(pb1 + k + 32);
        acc00 = __builtin_amdgcn_mfma_f32_16x16x32_bf16(a0, p0, acc00, 0, 0, 0);
        acc01 = __builtin_amdgcn_mfma_f32_16x16x32_bf16(a0, p1, acc01, 0, 0, 0);
        acc10 = __builtin_amdgcn_mfma_f32_16x16x32_bf16(a1, p0, acc10, 0, 0, 0);
        acc11 = __builtin_amdgcn_mfma_f32_16x16x32_bf16(a1, p1, acc11, 0, 0, 0);
        acc00 = __builtin_amdgcn_mfma_f32_16x16x32_bf16(a0b, p0b, acc00, 0, 0, 0);
        acc01 = __builtin_amdgcn_mfma_f32_16x16x32_bf16(a0b, p1b, acc01, 0, 0, 0);
        acc10 = __builtin_amdgcn_mfma_f32_16x16x32_bf16(a1b, p0b, acc10, 0, 0, 0);
        acc11 = __builtin_amdgcn_mfma_f32_16x16x32_bf16(a1b, p1b, acc11, 0, 0, 0);
    }

    float* partial = (float*)(ws + OFF_PARTIAL);
    int rl = (lane >> 4) * 4;
    #pragma unroll
    for (int r = 0; r < 4; r++){
        size_t rowA = (size_t)(kz*128 + n0 + rl + r)*BATCH;
        size_t rowB = (size_t)(kz*128 + n0 + 16 + rl + r)*BATCH;
        partial[rowA + b0 + l15]      = acc00[r];
        partial[rowA + b0 + 16 + l15] = acc01[r];
        partial[rowB + b0 + l15]      = acc10[r];
        partial[rowB + b0 + 16 + l15] = acc11[r];
    }
}

// ---------------- K5b: reduce 4 partials + bias + relu -> h3[n][b] f32 -------------
__global__ __launch_bounds__(256) void fc1red_k(const void* __restrict__ fc1b,
                                                uint8_t* __restrict__ ws){
    int t = blockIdx.x * 256 + threadIdx.x;  // t = n*4096 + b
    int b = t & 4095; int n = t >> 12;
    int ifmt = *(volatile int*)(ws + OFF_IFMT);
    const float* partial = (const float*)(ws + OFF_PARTIAL);
    float s = ldin(fc1b, n, ifmt);
    #pragma unroll
    for (int kc = 0; kc < 4; kc++) s += partial[(size_t)(kc*128 + n)*BATCH + b];
    ((float*)(ws + OFF_H3))[t] = fmaxf(s, 0.f);
}

// ---------------- K6: fc2 + log_softmax -> out [B][10] f32 -------------------------
__global__ __launch_bounds__(256) void fc2_k(const void* __restrict__ fc2b,
                                             uint8_t* __restrict__ ws,
                                             float* __restrict__ out){
    int b = blockIdx.x * 256 + threadIdx.x;  // 4096 threads
    int ifmt = *(volatile int*)(ws + OFF_IFMT);
    const float* h3   = (const float*)(ws + OFF_H3);
    const float* fc2t = (const float*)(ws + OFF_FC2T);
    float acc[10];
    #pragma unroll
    for (int n = 0; n < 10; n++) acc[n] = ldin(fc2b, n, ifmt);
    for (int k = 0; k < 128; k++){
        float v = h3[(size_t)k*BATCH + b];
        const float* wk = fc2t + k*10;
        #pragma unroll
        for (int n = 0; n < 10; n++) acc[n] = fmaf(v, wk[n], acc[n]);
    }
    float m = acc[0];
    #pragma unroll
    for (int n = 1; n < 10; n++) m = fmaxf(m, acc[n]);
    float s = 0.f;
    #pragma unroll
    for (int n = 0; n < 10; n++) s += expf(acc[n] - m);
    float ls = logf(s);
    #pragma unroll
    for (int n = 0; n < 10; n++) out[(size_t)b*10 + n] = acc[n] - m - ls;
}

extern "C" void kernel_launch(void* const* d_in, const int* in_sizes, int n_in,
                              void* d_out, int out_size, void* d_ws, size_t ws_size,
                              hipStream_t stream){
    const void* x    = d_in[0];
    const void* mask = d_in[1];
    const void* w1   = d_in[2];
    const void* w2   = d_in[3];
    const void* fc1w = d_in[4];
    const void* fc1b = d_in[5];
    const void* fc2w = d_in[6];
    const void* fc2b = d_in[7];
    uint8_t* ws = (uint8_t*)d_ws;
    float* out = (float*)d_out;

    hipLaunchKernelGGL(probe_k,     dim3(1),     dim3(256), 0, stream, mask, fc1w, ws);
    hipLaunchKernelGGL(prep_k,      dim3(72),    dim3(256), 0, stream, w1, w2, fc2w, ws);
    hipLaunchKernelGGL(fc1wb_k,     dim3(6272),  dim3(256), 0, stream, fc1w, ws);
    hipLaunchKernelGGL(count_k,     dim3(NBLK),  dim3(256), 0, stream, mask, ws);
    hipLaunchKernelGGL(scan_k,      dim3(1),     dim3(256), 0, stream, ws);
    hipLaunchKernelGGL(assign_k,    dim3(NBLK),  dim3(256), 0, stream, mask, ws);
    hipLaunchKernelGGL(conv1_k,     dim3(2560),  dim3(256), 0, stream, x, ws);
    hipLaunchKernelGGL(conv2mfma_k, dim3(2560),  dim3(256), 0, stream, ws);
    hipLaunchKernelGGL(pool_k,      dim3(4096),  dim3(256), 0, stream, ws);
    hipLaunchKernelGGL(fc1mfma_k,   dim3(512),   dim3(256), 0, stream, ws);
    hipLaunchKernelGGL(fc1red_k,    dim3(2048),  dim3(256), 0, stream, fc1b, ws);
    hipLaunchKernelGGL(fc2_k,       dim3(16),    dim3(256), 0, stream, fc2b, ws, out);
}